// Round 3
// baseline (4212.605 us; speedup 1.0000x reference)
//
#include <hip/hip_runtime.h>
#include <hip/hip_bf16.h>

typedef __attribute__((ext_vector_type(8))) short short8;
typedef __attribute__((ext_vector_type(4))) float floatx4;

#define GLD16(g, l) __builtin_amdgcn_global_load_lds( \
    (__attribute__((address_space(1))) void*)(g),      \
    (__attribute__((address_space(3))) void*)(l), 16, 0, 0)

#define MFMA_BF16(a, b, c) __builtin_amdgcn_mfma_f32_16x16x32_bf16((a), (b), (c), 0, 0, 0)

__device__ __forceinline__ short f2bf(float f) {
  union { __hip_bfloat16 h; short s; } u;
  u.h = __float2bfloat16(f);
  return u.s;
}

// bijective XCD-chunked swizzle (m204): contiguous work chunk per XCD
__device__ __forceinline__ int xcd_swz(int orig, int nwg) {
  const int xcd = orig & 7;
  const int idx = orig >> 3;
  const int q = nwg >> 3, r = nwg & 7;
  const int base = (xcd < r) ? xcd * (q + 1) : r * (q + 1) + (xcd - r) * q;
  return base + idx;
}

// ---------------------------------------------------------------------------
// transpose + fp32->bf16 convert:  in fp32 [K][N] -> out bf16 [Npad][K]
// ---------------------------------------------------------------------------
__global__ __launch_bounds__(256)
void transpose_convert(const float* __restrict__ in, short* __restrict__ out,
                       const int K, const int N, const size_t inStride,
                       const size_t outStride) {
  in += blockIdx.z * inStride;
  out += blockIdx.z * outStride;
  __shared__ float tile[32][33];
  const int n0 = blockIdx.x * 32;
  const int k0 = blockIdx.y * 32;
  const int tx = threadIdx.x;
  const int ty = threadIdx.y;
#pragma unroll
  for (int i = 0; i < 4; ++i) {
    const int kk = ty + i * 8;
    const int nn = n0 + tx;
    tile[kk][tx] = (nn < N) ? in[(size_t)(k0 + kk) * N + nn] : 0.f;
  }
  __syncthreads();
#pragma unroll
  for (int i = 0; i < 4; ++i) {
    const int nn = ty + i * 8;
    out[(size_t)(n0 + nn) * K + k0 + tx] = f2bf(tile[tx][nn]);
  }
}

// ---------------------------------------------------------------------------
__global__ __launch_bounds__(256)
void embed_kernel(const int* __restrict__ idx, const float* __restrict__ wte,
                  const float* __restrict__ wpe, float* __restrict__ x) {
  const int row = blockIdx.x;
  const int tok = idx[row];
  const int s = row & 1023;
  const float* wt = wte + (size_t)tok * 768;
  const float* wp = wpe + (size_t)s * 768;
  float* xr = x + (size_t)row * 768;
  for (int c = threadIdx.x; c < 768; c += 256) xr[c] = wt[c] + wp[c];
}

// ---------------------------------------------------------------------------
__global__ __launch_bounds__(256)
void ln_kernel(const float* __restrict__ x, const float* __restrict__ g,
               const float* __restrict__ b, short* __restrict__ out) {
  const int row = blockIdx.x;
  const int t = threadIdx.x;
  const int wv = t >> 6, lane = t & 63;
  const float* xr = x + (size_t)row * 768;
  const float v0 = xr[t], v1 = xr[t + 256], v2 = xr[t + 512];
  __shared__ float red[4];
  float s = v0 + v1 + v2;
#pragma unroll
  for (int m = 1; m < 64; m <<= 1) s += __shfl_xor(s, m);
  if (lane == 0) red[wv] = s;
  __syncthreads();
  const float mean = (red[0] + red[1] + red[2] + red[3]) * (1.0f / 768.0f);
  __syncthreads();
  const float d0 = v0 - mean, d1 = v1 - mean, d2 = v2 - mean;
  float q = d0 * d0 + d1 * d1 + d2 * d2;
#pragma unroll
  for (int m = 1; m < 64; m <<= 1) q += __shfl_xor(q, m);
  if (lane == 0) red[wv] = q;
  __syncthreads();
  const float var = (red[0] + red[1] + red[2] + red[3]) * (1.0f / 768.0f);
  const float inv = rsqrtf(var + 1e-5f);
  short* orow = out + (size_t)row * 768;
  orow[t] = f2bf(d0 * inv * g[t] + b[t]);
  orow[t + 256] = f2bf(d1 * inv * g[t + 256] + b[t + 256]);
  orow[t + 512] = f2bf(d2 * inv * g[t + 512] + b[t + 512]);
}

// ---------------------------------------------------------------------------
// GEMM 128x128, BK=32, 256 threads = 4 waves. Split-K via blockIdx.z
// (Kslice per slice, fp32 atomicAdd epilogue for EPI_RESID).
// ---------------------------------------------------------------------------
enum { EPI_QKV = 0, EPI_RESID = 1, EPI_GELU = 2 };

template <int EPI>
__global__ __launch_bounds__(256)
void gemm_kernel(const short* __restrict__ A, const short* __restrict__ Bt,
                 const int Kfull, const int Kslice,
                 const float* __restrict__ bias0, const float* __restrict__ bias1,
                 const float* __restrict__ bias2, float* __restrict__ fout,
                 short* __restrict__ bout0, short* __restrict__ bout1,
                 short* __restrict__ bout2) {
  const int gx = gridDim.x, gy = gridDim.y;
  const int nwg = gx * gy * gridDim.z;
  const int flat = (blockIdx.z * gy + blockIdx.y) * gx + blockIdx.x;
  const int wid = xcd_swz(flat, nwg);
  const int bz = wid / (gx * gy);
  const int rem = wid - bz * gx * gy;
  const int by = rem / gx;
  const int bx = rem - by * gx;

  __shared__ short sA[128 * 32];
  __shared__ short sB[128 * 32];
  const int tid = threadIdx.x;
  const int wv = tid >> 6;
  const int lane = tid & 63;
  const int lrow = lane & 15;
  const int lk8 = lane >> 4;
  const int m0 = bx * 128;
  const int n0 = by * 128;
  const int wm = (wv >> 1) * 64;
  const int wn = (wv & 1) * 64;

  floatx4 acc[4][4];
#pragma unroll
  for (int m = 0; m < 4; ++m)
#pragma unroll
    for (int n = 0; n < 4; ++n) acc[m][n] = {0.f, 0.f, 0.f, 0.f};

  const int e0 = tid * 8;
  const int r0 = e0 >> 5, c0 = e0 & 31;
  const int e1 = (256 + tid) * 8;
  const int r1 = e1 >> 5, c1 = e1 & 31;

  const short* Ab = A + (size_t)m0 * Kfull + bz * Kslice;
  const short* Bb = Bt + (size_t)n0 * Kfull + bz * Kslice;

  const int nk = Kslice >> 5;
  for (int kt = 0; kt < nk; ++kt) {
    const int kb = kt << 5;
    GLD16(Ab + (size_t)r0 * Kfull + kb + c0, sA + wv * 512);
    GLD16(Ab + (size_t)r1 * Kfull + kb + c1, sA + 2048 + wv * 512);
    GLD16(Bb + (size_t)r0 * Kfull + kb + c0, sB + wv * 512);
    GLD16(Bb + (size_t)r1 * Kfull + kb + c1, sB + 2048 + wv * 512);
    __syncthreads();
    short8 af[4], bfv[4];
#pragma unroll
    for (int m = 0; m < 4; ++m)
      af[m] = *(const short8*)(sA + (wm + m * 16 + lrow) * 32 + lk8 * 8);
#pragma unroll
    for (int n = 0; n < 4; ++n)
      bfv[n] = *(const short8*)(sB + (wn + n * 16 + lrow) * 32 + lk8 * 8);
#pragma unroll
    for (int m = 0; m < 4; ++m)
#pragma unroll
      for (int n = 0; n < 4; ++n)
        acc[m][n] = MFMA_BF16(af[m], bfv[n], acc[m][n]);
    __syncthreads();
  }

#pragma unroll
  for (int m = 0; m < 4; ++m) {
#pragma unroll
    for (int n = 0; n < 4; ++n) {
#pragma unroll
      for (int r = 0; r < 4; ++r) {
        const float v = acc[m][n][r];
        const int gm = m0 + wm + m * 16 + lk8 * 4 + r;
        const int gn = n0 + wn + n * 16 + lrow;
        if (EPI == EPI_QKV) {
          const int sec = (gn >= 1536) ? 2 : (gn >= 768 ? 1 : 0);
          const int nn = gn - sec * 768;
          const int hh = nn >> 6, dh = nn & 63;
          const int bb = gm >> 10, srow = gm & 1023;
          if (sec == 0) {
            bout0[(((size_t)(bb * 12 + hh) * 1024 + srow) << 6) + dh] =
                f2bf((v + bias0[nn]) * 0.125f);
          } else if (sec == 1) {
            bout1[(((size_t)(bb * 12 + hh) * 1024 + srow) << 6) + dh] =
                f2bf(v + bias1[nn]);
          } else {
            bout2[(((size_t)(bb * 12 + hh) * 64 + dh) << 10) + srow] =
                f2bf(v + bias2[nn]);
          }
        } else if (EPI == EPI_RESID) {
          const float add = v + (bz == 0 ? bias0[gn] : 0.f);
          atomicAdd(&fout[(size_t)gm * 768 + gn], add);
        } else {  // EPI_GELU
          const float tt = v + bias0[gn];
          const float gl = 0.5f * tt * (1.f + erff(tt * 0.70710678118654752f));
          bout0[(size_t)gm * 3072 + gn] = f2bf(gl);
        }
      }
    }
  }
}

// ---------------------------------------------------------------------------
// LM-head GEMM: 256x128 tile, BK=32, 512 threads = 8 waves (4Mx2N of 64x64)
// ---------------------------------------------------------------------------
__global__ __launch_bounds__(512)
void gemm_lm_kernel(const short* __restrict__ A, const short* __restrict__ Bt,
                    float* __restrict__ fout) {
  const int gx = gridDim.x;
  const int nwg = gx * gridDim.y;
  const int flat = blockIdx.y * gx + blockIdx.x;
  const int wid = xcd_swz(flat, nwg);
  const int bx = wid % gx;
  const int by = wid / gx;

  __shared__ short sA[256 * 32];
  __shared__ short sB[128 * 32];
  const int K = 768;
  const int tid = threadIdx.x;
  const int wv = tid >> 6;
  const int lane = tid & 63;
  const int lrow = lane & 15;
  const int lk8 = lane >> 4;
  const int m0 = bx * 256;
  const int n0 = by * 128;
  const int wm = (wv >> 1) * 64;
  const int wn = (wv & 1) * 64;

  floatx4 acc[4][4];
#pragma unroll
  for (int m = 0; m < 4; ++m)
#pragma unroll
    for (int n = 0; n < 4; ++n) acc[m][n] = {0.f, 0.f, 0.f, 0.f};

  const int eA0 = tid, eA1 = 512 + tid, eB = tid;
  const int rA0 = eA0 >> 2, cA0 = (eA0 & 3) * 8;
  const int rA1 = eA1 >> 2, cA1 = (eA1 & 3) * 8;
  const int rB = eB >> 2, cB = (eB & 3) * 8;

  const short* Ab = A + (size_t)m0 * K;
  const short* Bb = Bt + (size_t)n0 * K;

  for (int kt = 0; kt < 24; ++kt) {
    const int kb = kt << 5;
    GLD16(Ab + (size_t)rA0 * K + kb + cA0, sA + wv * 512);
    GLD16(Ab + (size_t)rA1 * K + kb + cA1, sA + 4096 + wv * 512);
    GLD16(Bb + (size_t)rB * K + kb + cB, sB + wv * 512);
    __syncthreads();
    short8 af[4], bfv[4];
#pragma unroll
    for (int m = 0; m < 4; ++m)
      af[m] = *(const short8*)(sA + (wm + m * 16 + lrow) * 32 + lk8 * 8);
#pragma unroll
    for (int n = 0; n < 4; ++n)
      bfv[n] = *(const short8*)(sB + (wn + n * 16 + lrow) * 32 + lk8 * 8);
#pragma unroll
    for (int m = 0; m < 4; ++m)
#pragma unroll
      for (int n = 0; n < 4; ++n)
        acc[m][n] = MFMA_BF16(af[m], bfv[n], acc[m][n]);
    __syncthreads();
  }

#pragma unroll
  for (int m = 0; m < 4; ++m)
#pragma unroll
    for (int n = 0; n < 4; ++n)
#pragma unroll
      for (int r = 0; r < 4; ++r) {
        const int gm = m0 + wm + m * 16 + lk8 * 4 + r;
        const int gn = n0 + wn + n * 16 + lrow;
        if (gn < 50257) fout[(size_t)gm * 50257 + gn] = acc[m][n][r];
      }
}

// ---------------------------------------------------------------------------
// flash attention (causal), LDS-staged K/V (r1-proven), XCD swizzle by head.
// q,k [48][1024][64] bf16 (q pre-scaled 1/8), vt [48][64][1024] bf16
// -> o [4096][768] bf16. grid (48,16), block 256.
// ---------------------------------------------------------------------------
__global__ __launch_bounds__(256)
void attn_kernel(const short* __restrict__ q, const short* __restrict__ k,
                 const short* __restrict__ vt, short* __restrict__ o) {
  __shared__ short sK[64 * 64];
  __shared__ short sV[64 * 64];
  __shared__ short sP[4][16 * 64];
  const int flat = blockIdx.y * 48 + blockIdx.x;
  const int wid = xcd_swz(flat, 768);
  const int bh = wid >> 4;   // head-major: all 16 q-blocks of a head on one XCD
  const int qi = wid & 15;
  const int tid = threadIdx.x;
  const int wv = tid >> 6, lane = tid & 63;
  const int lrow = lane & 15, lk8 = lane >> 4;
  const int q0 = qi * 64;

  const short* qg = q + ((size_t)(bh * 1024 + q0 + wv * 16 + lrow)) * 64 + lk8 * 8;
  const short8 qf0 = *(const short8*)qg;
  const short8 qf1 = *(const short8*)(qg + 32);

  float m_run[4], lsum[4];
  floatx4 accO[4];
#pragma unroll
  for (int r = 0; r < 4; ++r) { m_run[r] = -1e30f; lsum[r] = 0.f; }
#pragma unroll
  for (int n = 0; n < 4; ++n) accO[n] = {0.f, 0.f, 0.f, 0.f};

  for (int t = 0; t <= qi; ++t) {
    const int k0 = t * 64;
#pragma unroll
    for (int i = 0; i < 2; ++i) {
      const int e = (i * 256 + tid) * 8;
      const int r = e >> 6, cc = e & 63;
      const int su = ((cc >> 3) ^ (r & 7)) << 3;
      *(short8*)(sK + r * 64 + su) =
          *(const short8*)(k + ((size_t)(bh * 1024 + k0 + r)) * 64 + cc);
      *(short8*)(sV + r * 64 + su) =
          *(const short8*)(vt + ((size_t)(bh * 64 + r)) * 1024 + k0 + cc);
    }
    __syncthreads();

    floatx4 accS[4];
#pragma unroll
    for (int n = 0; n < 4; ++n) accS[n] = {0.f, 0.f, 0.f, 0.f};
#pragma unroll
    for (int ks = 0; ks < 2; ++ks) {
      const short8 qf = ks ? qf1 : qf0;
      const int u = lk8 + ks * 4;
#pragma unroll
      for (int n = 0; n < 4; ++n) {
        const int key = n * 16 + lrow;
        const short8 kf = *(const short8*)(sK + key * 64 + ((u ^ (key & 7)) << 3));
        accS[n] = MFMA_BF16(qf, kf, accS[n]);
      }
    }

#pragma unroll
    for (int r = 0; r < 4; ++r) {
      const int qrow = q0 + wv * 16 + lk8 * 4 + r;
      float sv[4];
      float mx = -1e30f;
#pragma unroll
      for (int n = 0; n < 4; ++n) {
        float s = accS[n][r];
        const int key = k0 + n * 16 + lrow;
        s = (key > qrow) ? -1e30f : s;
        sv[n] = s;
        mx = fmaxf(mx, s);
      }
#pragma unroll
      for (int m = 1; m < 16; m <<= 1) mx = fmaxf(mx, __shfl_xor(mx, m));
      const float mnew = fmaxf(m_run[r], mx);
      const float sf = __expf(m_run[r] - mnew);
      m_run[r] = mnew;
      float rs = 0.f;
      const int prow = lk8 * 4 + r;
#pragma unroll
      for (int n = 0; n < 4; ++n) {
        const float pv = __expf(sv[n] - mnew);
        rs += pv;
        const int col = n * 16 + lrow;
        sP[wv][prow * 64 + (((col >> 3) ^ (prow & 7)) << 3) + (col & 7)] = f2bf(pv);
      }
#pragma unroll
      for (int m = 1; m < 16; m <<= 1) rs += __shfl_xor(rs, m);
      lsum[r] = lsum[r] * sf + rs;
#pragma unroll
      for (int n = 0; n < 4; ++n) accO[n][r] *= sf;
    }

#pragma unroll
    for (int ks = 0; ks < 2; ++ks) {
      const int u = lk8 + ks * 4;
      const short8 pf =
          *(const short8*)(&sP[wv][lrow * 64 + ((u ^ (lrow & 7)) << 3)]);
#pragma unroll
      for (int n = 0; n < 4; ++n) {
        const int dh = n * 16 + lrow;
        const short8 vf = *(const short8*)(sV + dh * 64 + ((u ^ (dh & 7)) << 3));
        accO[n] = MFMA_BF16(pf, vf, accO[n]);
      }
    }
    __syncthreads();
  }

  const int bb = bh / 12, hh = bh % 12;
#pragma unroll
  for (int n = 0; n < 4; ++n)
#pragma unroll
    for (int r = 0; r < 4; ++r) {
      const int row = q0 + wv * 16 + lk8 * 4 + r;
      const float ov = accO[n][r] / lsum[r];
      o[((size_t)(bb * 1024 + row)) * 768 + hh * 64 + n * 16 + lrow] = f2bf(ov);
    }
}

// ---------------------------------------------------------------------------
extern "C" void kernel_launch(void* const* d_in, const int* in_sizes, int n_in,
                              void* d_out, int out_size, void* d_ws, size_t ws_size,
                              hipStream_t stream) {
  const int* idx = (const int*)d_in[0];
  const float* wte = (const float*)d_in[1];
  const float* wpe = (const float*)d_in[2];
  const float* ln1_g = (const float*)d_in[3];
  const float* ln1_b = (const float*)d_in[4];
  const float* wq = (const float*)d_in[5];
  const float* bq = (const float*)d_in[6];
  const float* wk = (const float*)d_in[7];
  const float* bk = (const float*)d_in[8];
  const float* wv = (const float*)d_in[9];
  const float* bv = (const float*)d_in[10];
  const float* wo = (const float*)d_in[11];
  const float* bo = (const float*)d_in[12];
  const float* ln2_g = (const float*)d_in[13];
  const float* ln2_b = (const float*)d_in[14];
  const float* w1 = (const float*)d_in[15];
  const float* b1 = (const float*)d_in[16];
  const float* w2 = (const float*)d_in[17];
  const float* b2 = (const float*)d_in[18];
  const float* lnf_g = (const float*)d_in[19];
  const float* lnf_b = (const float*)d_in[20];
  const float* lm_w = (const float*)d_in[21];
  float* out = (float*)d_out;

  char* base = (char*)d_ws;
  size_t off = 0;
  auto alloc = [&](size_t bytes) {
    char* r = base + off;
    off = (off + bytes + 255) & ~(size_t)255;
    return r;
  };
  short* lmT = (short*)alloc((size_t)50304 * 768 * 2);
  float* x = (float*)alloc((size_t)4096 * 768 * 4);
  short* h = (short*)alloc((size_t)4096 * 768 * 2);
  short* qb = (short*)alloc((size_t)4096 * 768 * 2);
  short* kb = (short*)alloc((size_t)4096 * 768 * 2);
  short* vtb = (short*)alloc((size_t)4096 * 768 * 2);
  short* ob = (short*)alloc((size_t)4096 * 768 * 2);
  short* ff = (short*)alloc((size_t)4096 * 3072 * 2);

  const size_t LW = 7077888;  // elements per layer weight block
  const size_t dd = (size_t)768 * 768;
  const bool big = (off + (size_t)12 * LW * 2 + 256 <= ws_size);
  short* wAll = nullptr;
  short *wqkvT = nullptr, *woT = nullptr, *w1T = nullptr, *w2T = nullptr;
  if (big) {
    wAll = (short*)alloc((size_t)12 * LW * 2);
  } else {
    wqkvT = (short*)alloc((size_t)2304 * 768 * 2);
    woT = (short*)alloc((size_t)768 * 768 * 2);
    w1T = (short*)alloc((size_t)3072 * 768 * 2);
    w2T = (short*)alloc((size_t)768 * 3072 * 2);
    if (off > ws_size) return;
  }

  const dim3 tb(32, 8);
  transpose_convert<<<dim3(1572, 24, 1), tb, 0, stream>>>(lm_w, lmT, 768, 50257, 0, 0);
  if (big) {
    transpose_convert<<<dim3(24, 24, 12), tb, 0, stream>>>(wq, wAll + 0, 768, 768, dd, LW);
    transpose_convert<<<dim3(24, 24, 12), tb, 0, stream>>>(wk, wAll + 589824, 768, 768, dd, LW);
    transpose_convert<<<dim3(24, 24, 12), tb, 0, stream>>>(wv, wAll + 1179648, 768, 768, dd, LW);
    transpose_convert<<<dim3(24, 24, 12), tb, 0, stream>>>(wo, wAll + 1769472, 768, 768, dd, LW);
    transpose_convert<<<dim3(96, 24, 12), tb, 0, stream>>>(w1, wAll + 2359296, 768, 3072,
                                                           (size_t)768 * 3072, LW);
    transpose_convert<<<dim3(24, 96, 12), tb, 0, stream>>>(w2, wAll + 4718592, 3072, 768,
                                                           (size_t)3072 * 768, LW);
  }
  embed_kernel<<<4096, 256, 0, stream>>>(idx, wte, wpe, x);

  for (int l = 0; l < 12; ++l) {
    const short *pQKV, *pWO, *pW1, *pW2;
    if (big) {
      short* wl = wAll + (size_t)l * LW;
      pQKV = wl;
      pWO = wl + 1769472;
      pW1 = wl + 2359296;
      pW2 = wl + 4718592;
    } else {
      transpose_convert<<<dim3(24, 24, 1), tb, 0, stream>>>(wq + l * dd, wqkvT, 768, 768, 0, 0);
      transpose_convert<<<dim3(24, 24, 1), tb, 0, stream>>>(wk + l * dd, wqkvT + dd, 768, 768, 0, 0);
      transpose_convert<<<dim3(24, 24, 1), tb, 0, stream>>>(wv + l * dd, wqkvT + 2 * dd, 768, 768, 0, 0);
      transpose_convert<<<dim3(24, 24, 1), tb, 0, stream>>>(wo + l * dd, woT, 768, 768, 0, 0);
      transpose_convert<<<dim3(96, 24, 1), tb, 0, stream>>>(w1 + (size_t)l * 768 * 3072, w1T, 768, 3072, 0, 0);
      transpose_convert<<<dim3(24, 96, 1), tb, 0, stream>>>(w2 + (size_t)l * 3072 * 768, w2T, 3072, 768, 0, 0);
      pQKV = wqkvT; pWO = woT; pW1 = w1T; pW2 = w2T;
    }

    ln_kernel<<<4096, 256, 0, stream>>>(x, ln1_g + l * 768, ln1_b + l * 768, h);
    gemm_kernel<EPI_QKV><<<dim3(32, 18, 1), 256, 0, stream>>>(
        h, pQKV, 768, 768, bq + l * 768, bk + l * 768, bv + l * 768, nullptr, qb, kb, vtb);
    attn_kernel<<<dim3(48, 16), 256, 0, stream>>>(qb, kb, vtb, ob);
    gemm_kernel<EPI_RESID><<<dim3(32, 6, 2), 256, 0, stream>>>(
        ob, pWO, 768, 384, bo + l * 768, nullptr, nullptr, x, nullptr, nullptr, nullptr);
    ln_kernel<<<4096, 256, 0, stream>>>(x, ln2_g + l * 768, ln2_b + l * 768, h);
    gemm_kernel<EPI_GELU><<<dim3(32, 24, 1), 256, 0, stream>>>(
        h, pW1, 768, 768, b1 + l * 3072, nullptr, nullptr, nullptr, ff, nullptr, nullptr);
    gemm_kernel<EPI_RESID><<<dim3(32, 6, 4), 256, 0, stream>>>(
        ff, pW2, 3072, 768, b2 + l * 768, nullptr, nullptr, x, nullptr, nullptr, nullptr);
  }

  ln_kernel<<<4096, 256, 0, stream>>>(x, lnf_g, lnf_b, h);
  gemm_lm_kernel<<<dim3(16, 393), 512, 0, stream>>>(h, lmT, out);
}

// Round 4
// 3757.493 us; speedup vs baseline: 1.1211x; 1.1211x over previous
//
#include <hip/hip_runtime.h>
#include <hip/hip_bf16.h>

typedef __attribute__((ext_vector_type(8))) short short8;
typedef __attribute__((ext_vector_type(4))) float floatx4;

#define GLD16(g, l) __builtin_amdgcn_global_load_lds( \
    (__attribute__((address_space(1))) void*)(g),      \
    (__attribute__((address_space(3))) void*)(l), 16, 0, 0)

#define MFMA_BF16(a, b, c) __builtin_amdgcn_mfma_f32_16x16x32_bf16((a), (b), (c), 0, 0, 0)

__device__ __forceinline__ short f2bf(float f) {
  union { __hip_bfloat16 h; short s; } u;
  u.h = __float2bfloat16(f);
  return u.s;
}

// ---------------------------------------------------------------------------
// transpose + fp32->bf16 convert:  in fp32 [K][N] -> out bf16 [Npad][K]
// ---------------------------------------------------------------------------
__global__ __launch_bounds__(256)
void transpose_convert(const float* __restrict__ in, short* __restrict__ out,
                       const int K, const int N, const size_t inStride,
                       const size_t outStride) {
  in += blockIdx.z * inStride;
  out += blockIdx.z * outStride;
  __shared__ float tile[32][33];
  const int n0 = blockIdx.x * 32;
  const int k0 = blockIdx.y * 32;
  const int tx = threadIdx.x;
  const int ty = threadIdx.y;
#pragma unroll
  for (int i = 0; i < 4; ++i) {
    const int kk = ty + i * 8;
    const int nn = n0 + tx;
    tile[kk][tx] = (nn < N) ? in[(size_t)(k0 + kk) * N + nn] : 0.f;
  }
  __syncthreads();
#pragma unroll
  for (int i = 0; i < 4; ++i) {
    const int nn = ty + i * 8;
    out[(size_t)(n0 + nn) * K + k0 + tx] = f2bf(tile[tx][nn]);
  }
}

// ---------------------------------------------------------------------------
__global__ __launch_bounds__(256)
void embed_kernel(const int* __restrict__ idx, const float* __restrict__ wte,
                  const float* __restrict__ wpe, float* __restrict__ x) {
  const int row = blockIdx.x;
  const int tok = idx[row];
  const int s = row & 1023;
  const float* wt = wte + (size_t)tok * 768;
  const float* wp = wpe + (size_t)s * 768;
  float* xr = x + (size_t)row * 768;
  for (int c = threadIdx.x; c < 768; c += 256) xr[c] = wt[c] + wp[c];
}

// ---------------------------------------------------------------------------
__global__ __launch_bounds__(256)
void ln_kernel(const float* __restrict__ x, const float* __restrict__ g,
               const float* __restrict__ b, short* __restrict__ out) {
  const int row = blockIdx.x;
  const int t = threadIdx.x;
  const int wv = t >> 6, lane = t & 63;
  const float* xr = x + (size_t)row * 768;
  const float v0 = xr[t], v1 = xr[t + 256], v2 = xr[t + 512];
  __shared__ float red[4];
  float s = v0 + v1 + v2;
#pragma unroll
  for (int m = 1; m < 64; m <<= 1) s += __shfl_xor(s, m);
  if (lane == 0) red[wv] = s;
  __syncthreads();
  const float mean = (red[0] + red[1] + red[2] + red[3]) * (1.0f / 768.0f);
  __syncthreads();
  const float d0 = v0 - mean, d1 = v1 - mean, d2 = v2 - mean;
  float q = d0 * d0 + d1 * d1 + d2 * d2;
#pragma unroll
  for (int m = 1; m < 64; m <<= 1) q += __shfl_xor(q, m);
  if (lane == 0) red[wv] = q;
  __syncthreads();
  const float var = (red[0] + red[1] + red[2] + red[3]) * (1.0f / 768.0f);
  const float inv = rsqrtf(var + 1e-5f);
  short* orow = out + (size_t)row * 768;
  orow[t] = f2bf(d0 * inv * g[t] + b[t]);
  orow[t + 256] = f2bf(d1 * inv * g[t + 256] + b[t + 256]);
  orow[t + 512] = f2bf(d2 * inv * g[t + 512] + b[t + 512]);
}

// ---------------------------------------------------------------------------
// GEMM 128x128, BK=32, 256 threads = 4 waves, double-buffered LDS:
// issue next-tile global_load_lds BEFORE compute of current tile; one
// __syncthreads() per K-step (its implicit vmcnt(0) drain completes stage).
// ---------------------------------------------------------------------------
enum { EPI_QKV = 0, EPI_RESID = 1, EPI_GELU = 2 };

template <int EPI>
__global__ __launch_bounds__(256)
void gemm_kernel(const short* __restrict__ A, const short* __restrict__ Bt,
                 const int K,
                 const float* __restrict__ bias0, const float* __restrict__ bias1,
                 const float* __restrict__ bias2, float* __restrict__ fout,
                 short* __restrict__ bout0, short* __restrict__ bout1,
                 short* __restrict__ bout2) {
  __shared__ short sA[2][128 * 32];
  __shared__ short sB[2][128 * 32];
  const int tid = threadIdx.x;
  const int wv = tid >> 6;
  const int lane = tid & 63;
  const int lrow = lane & 15;
  const int lk8 = lane >> 4;
  const int m0 = blockIdx.x * 128;
  const int n0 = blockIdx.y * 128;
  const int wm = (wv >> 1) * 64;
  const int wn = (wv & 1) * 64;

  floatx4 acc[4][4];
#pragma unroll
  for (int m = 0; m < 4; ++m)
#pragma unroll
    for (int n = 0; n < 4; ++n) acc[m][n] = {0.f, 0.f, 0.f, 0.f};

  const int e0 = tid * 8;
  const int r0 = e0 >> 5, c0 = e0 & 31;
  const int e1 = (256 + tid) * 8;
  const int r1 = e1 >> 5, c1 = e1 & 31;

  const short* Ab = A + (size_t)m0 * K;
  const short* Bb = Bt + (size_t)n0 * K;

  const int nk = K >> 5;
  // prologue: stage tile 0 into buffer 0
  GLD16(Ab + (size_t)r0 * K + c0, sA[0] + wv * 512);
  GLD16(Ab + (size_t)r1 * K + c1, sA[0] + 2048 + wv * 512);
  GLD16(Bb + (size_t)r0 * K + c0, sB[0] + wv * 512);
  GLD16(Bb + (size_t)r1 * K + c1, sB[0] + 2048 + wv * 512);
  __syncthreads();

  int cur = 0;
  for (int kt = 0; kt < nk; ++kt) {
    if (kt + 1 < nk) {
      const int kb = (kt + 1) << 5;
      GLD16(Ab + (size_t)r0 * K + kb + c0, sA[cur ^ 1] + wv * 512);
      GLD16(Ab + (size_t)r1 * K + kb + c1, sA[cur ^ 1] + 2048 + wv * 512);
      GLD16(Bb + (size_t)r0 * K + kb + c0, sB[cur ^ 1] + wv * 512);
      GLD16(Bb + (size_t)r1 * K + kb + c1, sB[cur ^ 1] + 2048 + wv * 512);
    }
    short8 af[4], bfv[4];
#pragma unroll
    for (int m = 0; m < 4; ++m)
      af[m] = *(const short8*)(sA[cur] + (wm + m * 16 + lrow) * 32 + lk8 * 8);
#pragma unroll
    for (int n = 0; n < 4; ++n)
      bfv[n] = *(const short8*)(sB[cur] + (wn + n * 16 + lrow) * 32 + lk8 * 8);
#pragma unroll
    for (int m = 0; m < 4; ++m)
#pragma unroll
      for (int n = 0; n < 4; ++n)
        acc[m][n] = MFMA_BF16(af[m], bfv[n], acc[m][n]);
    __syncthreads();
    cur ^= 1;
  }

#pragma unroll
  for (int m = 0; m < 4; ++m) {
#pragma unroll
    for (int n = 0; n < 4; ++n) {
#pragma unroll
      for (int r = 0; r < 4; ++r) {
        const float v = acc[m][n][r];
        const int gm = m0 + wm + m * 16 + lk8 * 4 + r;
        const int gn = n0 + wn + n * 16 + lrow;
        if (EPI == EPI_QKV) {
          const int sec = (gn >= 1536) ? 2 : (gn >= 768 ? 1 : 0);
          const int nn = gn - sec * 768;
          const int hh = nn >> 6, dh = nn & 63;
          const int bb = gm >> 10, srow = gm & 1023;
          if (sec == 0) {
            bout0[(((size_t)(bb * 12 + hh) * 1024 + srow) << 6) + dh] =
                f2bf((v + bias0[nn]) * 0.125f);
          } else if (sec == 1) {
            bout1[(((size_t)(bb * 12 + hh) * 1024 + srow) << 6) + dh] =
                f2bf(v + bias1[nn]);
          } else {
            bout2[(((size_t)(bb * 12 + hh) * 64 + dh) << 10) + srow] =
                f2bf(v + bias2[nn]);
          }
        } else if (EPI == EPI_RESID) {
          float* xp = fout + (size_t)gm * 768 + gn;
          *xp = *xp + v + bias0[gn];
        } else {  // EPI_GELU
          const float tt = v + bias0[gn];
          const float gl = 0.5f * tt * (1.f + erff(tt * 0.70710678118654752f));
          bout0[(size_t)gm * 3072 + gn] = f2bf(gl);
        }
      }
    }
  }
}

// ---------------------------------------------------------------------------
// LM-head GEMM: 256x128 tile, BK=32, 512 threads = 8 waves, double-buffered.
// Natural dispatch order (bx%8 pins A-panels per XCD — measured r2 vs r3).
// ---------------------------------------------------------------------------
__global__ __launch_bounds__(512)
void gemm_lm_kernel(const short* __restrict__ A, const short* __restrict__ Bt,
                    float* __restrict__ fout) {
  __shared__ short sA[2][256 * 32];
  __shared__ short sB[2][128 * 32];
  const int K = 768;
  const int tid = threadIdx.x;
  const int wv = tid >> 6;
  const int lane = tid & 63;
  const int lrow = lane & 15;
  const int lk8 = lane >> 4;
  const int m0 = blockIdx.x * 256;
  const int n0 = blockIdx.y * 128;
  const int wm = (wv >> 1) * 64;
  const int wn = (wv & 1) * 64;

  floatx4 acc[4][4];
#pragma unroll
  for (int m = 0; m < 4; ++m)
#pragma unroll
    for (int n = 0; n < 4; ++n) acc[m][n] = {0.f, 0.f, 0.f, 0.f};

  const int rA0 = tid >> 2, cA0 = (tid & 3) * 8;
  const int rA1 = 128 + (tid >> 2), cA1 = (tid & 3) * 8;
  const int rB = tid >> 2, cB = (tid & 3) * 8;

  const short* Ab = A + (size_t)m0 * K;
  const short* Bb = Bt + (size_t)n0 * K;

  GLD16(Ab + (size_t)rA0 * K + cA0, sA[0] + wv * 512);
  GLD16(Ab + (size_t)rA1 * K + cA1, sA[0] + 4096 + wv * 512);
  GLD16(Bb + (size_t)rB * K + cB, sB[0] + wv * 512);
  __syncthreads();

  int cur = 0;
  for (int kt = 0; kt < 24; ++kt) {
    if (kt + 1 < 24) {
      const int kb = (kt + 1) << 5;
      GLD16(Ab + (size_t)rA0 * K + kb + cA0, sA[cur ^ 1] + wv * 512);
      GLD16(Ab + (size_t)rA1 * K + kb + cA1, sA[cur ^ 1] + 4096 + wv * 512);
      GLD16(Bb + (size_t)rB * K + kb + cB, sB[cur ^ 1] + wv * 512);
    }
    short8 af[4], bfv[4];
#pragma unroll
    for (int m = 0; m < 4; ++m)
      af[m] = *(const short8*)(sA[cur] + (wm + m * 16 + lrow) * 32 + lk8 * 8);
#pragma unroll
    for (int n = 0; n < 4; ++n)
      bfv[n] = *(const short8*)(sB[cur] + (wn + n * 16 + lrow) * 32 + lk8 * 8);
#pragma unroll
    for (int m = 0; m < 4; ++m)
#pragma unroll
      for (int n = 0; n < 4; ++n)
        acc[m][n] = MFMA_BF16(af[m], bfv[n], acc[m][n]);
    __syncthreads();
    cur ^= 1;
  }

#pragma unroll
  for (int m = 0; m < 4; ++m)
#pragma unroll
    for (int n = 0; n < 4; ++n)
#pragma unroll
      for (int r = 0; r < 4; ++r) {
        const int gm = m0 + wm + m * 16 + lk8 * 4 + r;
        const int gn = n0 + wn + n * 16 + lrow;
        if (gn < 50257) fout[(size_t)gm * 50257 + gn] = acc[m][n][r];
      }
}

// ---------------------------------------------------------------------------
// flash attention (causal), LDS-staged K/V. Heavy q-blocks launch first
// (qi = 15 - blockIdx.y). Natural bh order gives per-head XCD affinity.
// q,k [48][1024][64] bf16 (q pre-scaled 1/8), vt [48][64][1024] bf16
// -> o [4096][768] bf16. grid (48,16), block 256.
// ---------------------------------------------------------------------------
__global__ __launch_bounds__(256)
void attn_kernel(const short* __restrict__ q, const short* __restrict__ k,
                 const short* __restrict__ vt, short* __restrict__ o) {
  __shared__ short sK[64 * 64];
  __shared__ short sV[64 * 64];
  __shared__ short sP[4][16 * 64];
  const int bh = blockIdx.x;
  const int qi = 15 - blockIdx.y;
  const int tid = threadIdx.x;
  const int wv = tid >> 6, lane = tid & 63;
  const int lrow = lane & 15, lk8 = lane >> 4;
  const int q0 = qi * 64;

  const short* qg = q + ((size_t)(bh * 1024 + q0 + wv * 16 + lrow)) * 64 + lk8 * 8;
  const short8 qf0 = *(const short8*)qg;
  const short8 qf1 = *(const short8*)(qg + 32);

  float m_run[4], lsum[4];
  floatx4 accO[4];
#pragma unroll
  for (int r = 0; r < 4; ++r) { m_run[r] = -1e30f; lsum[r] = 0.f; }
#pragma unroll
  for (int n = 0; n < 4; ++n) accO[n] = {0.f, 0.f, 0.f, 0.f};

  for (int t = 0; t <= qi; ++t) {
    const int k0 = t * 64;
#pragma unroll
    for (int i = 0; i < 2; ++i) {
      const int e = (i * 256 + tid) * 8;
      const int r = e >> 6, cc = e & 63;
      const int su = ((cc >> 3) ^ (r & 7)) << 3;
      *(short8*)(sK + r * 64 + su) =
          *(const short8*)(k + ((size_t)(bh * 1024 + k0 + r)) * 64 + cc);
      *(short8*)(sV + r * 64 + su) =
          *(const short8*)(vt + ((size_t)(bh * 64 + r)) * 1024 + k0 + cc);
    }
    __syncthreads();

    floatx4 accS[4];
#pragma unroll
    for (int n = 0; n < 4; ++n) accS[n] = {0.f, 0.f, 0.f, 0.f};
#pragma unroll
    for (int ks = 0; ks < 2; ++ks) {
      const short8 qf = ks ? qf1 : qf0;
      const int u = lk8 + ks * 4;
#pragma unroll
      for (int n = 0; n < 4; ++n) {
        const int key = n * 16 + lrow;
        const short8 kf = *(const short8*)(sK + key * 64 + ((u ^ (key & 7)) << 3));
        accS[n] = MFMA_BF16(qf, kf, accS[n]);
      }
    }

#pragma unroll
    for (int r = 0; r < 4; ++r) {
      const int qrow = q0 + wv * 16 + lk8 * 4 + r;
      float sv[4];
      float mx = -1e30f;
#pragma unroll
      for (int n = 0; n < 4; ++n) {
        float s = accS[n][r];
        const int key = k0 + n * 16 + lrow;
        s = (key > qrow) ? -1e30f : s;
        sv[n] = s;
        mx = fmaxf(mx, s);
      }
#pragma unroll
      for (int m = 1; m < 16; m <<= 1) mx = fmaxf(mx, __shfl_xor(mx, m));
      const float mnew = fmaxf(m_run[r], mx);
      const float sf = __expf(m_run[r] - mnew);
      m_run[r] = mnew;
      float rs = 0.f;
      const int prow = lk8 * 4 + r;
#pragma unroll
      for (int n = 0; n < 4; ++n) {
        const float pv = __expf(sv[n] - mnew);
        rs += pv;
        const int col = n * 16 + lrow;
        sP[wv][prow * 64 + (((col >> 3) ^ (prow & 7)) << 3) + (col & 7)] = f2bf(pv);
      }
#pragma unroll
      for (int m = 1; m < 16; m <<= 1) rs += __shfl_xor(rs, m);
      lsum[r] = lsum[r] * sf + rs;
#pragma unroll
      for (int n = 0; n < 4; ++n) accO[n][r] *= sf;
    }

#pragma unroll
    for (int ks = 0; ks < 2; ++ks) {
      const int u = lk8 + ks * 4;
      const short8 pf =
          *(const short8*)(&sP[wv][lrow * 64 + ((u ^ (lrow & 7)) << 3)]);
#pragma unroll
      for (int n = 0; n < 4; ++n) {
        const int dh = n * 16 + lrow;
        const short8 vf = *(const short8*)(sV + dh * 64 + ((u ^ (dh & 7)) << 3));
        accO[n] = MFMA_BF16(pf, vf, accO[n]);
      }
    }
    __syncthreads();
  }

  const int bb = bh / 12, hh = bh % 12;
#pragma unroll
  for (int n = 0; n < 4; ++n)
#pragma unroll
    for (int r = 0; r < 4; ++r) {
      const int row = q0 + wv * 16 + lk8 * 4 + r;
      const float ov = accO[n][r] / lsum[r];
      o[((size_t)(bb * 1024 + row)) * 768 + hh * 64 + n * 16 + lrow] = f2bf(ov);
    }
}

// ---------------------------------------------------------------------------
extern "C" void kernel_launch(void* const* d_in, const int* in_sizes, int n_in,
                              void* d_out, int out_size, void* d_ws, size_t ws_size,
                              hipStream_t stream) {
  const int* idx = (const int*)d_in[0];
  const float* wte = (const float*)d_in[1];
  const float* wpe = (const float*)d_in[2];
  const float* ln1_g = (const float*)d_in[3];
  const float* ln1_b = (const float*)d_in[4];
  const float* wq = (const float*)d_in[5];
  const float* bq = (const float*)d_in[6];
  const float* wk = (const float*)d_in[7];
  const float* bk = (const float*)d_in[8];
  const float* wv = (const float*)d_in[9];
  const float* bv = (const float*)d_in[10];
  const float* wo = (const float*)d_in[11];
  const float* bo = (const float*)d_in[12];
  const float* ln2_g = (const float*)d_in[13];
  const float* ln2_b = (const float*)d_in[14];
  const float* w1 = (const float*)d_in[15];
  const float* b1 = (const float*)d_in[16];
  const float* w2 = (const float*)d_in[17];
  const float* b2 = (const float*)d_in[18];
  const float* lnf_g = (const float*)d_in[19];
  const float* lnf_b = (const float*)d_in[20];
  const float* lm_w = (const float*)d_in[21];
  float* out = (float*)d_out;

  char* base = (char*)d_ws;
  size_t off = 0;
  auto alloc = [&](size_t bytes) {
    char* r = base + off;
    off = (off + bytes + 255) & ~(size_t)255;
    return r;
  };
  short* lmT = (short*)alloc((size_t)50304 * 768 * 2);
  float* x = (float*)alloc((size_t)4096 * 768 * 4);
  short* h = (short*)alloc((size_t)4096 * 768 * 2);
  short* qb = (short*)alloc((size_t)4096 * 768 * 2);
  short* kb = (short*)alloc((size_t)4096 * 768 * 2);
  short* vtb = (short*)alloc((size_t)4096 * 768 * 2);
  short* ob = (short*)alloc((size_t)4096 * 768 * 2);
  short* ff = (short*)alloc((size_t)4096 * 3072 * 2);

  const size_t LW = 7077888;  // elements per layer weight block
  const size_t dd = (size_t)768 * 768;
  const bool big = (off + (size_t)12 * LW * 2 + 256 <= ws_size);
  short* wAll = nullptr;
  short *wqkvT = nullptr, *woT = nullptr, *w1T = nullptr, *w2T = nullptr;
  if (big) {
    wAll = (short*)alloc((size_t)12 * LW * 2);
  } else {
    wqkvT = (short*)alloc((size_t)2304 * 768 * 2);
    woT = (short*)alloc((size_t)768 * 768 * 2);
    w1T = (short*)alloc((size_t)3072 * 768 * 2);
    w2T = (short*)alloc((size_t)768 * 3072 * 2);
    if (off > ws_size) return;
  }

  const dim3 tb(32, 8);
  transpose_convert<<<dim3(1572, 24, 1), tb, 0, stream>>>(lm_w, lmT, 768, 50257, 0, 0);
  if (big) {
    transpose_convert<<<dim3(24, 24, 12), tb, 0, stream>>>(wq, wAll + 0, 768, 768, dd, LW);
    transpose_convert<<<dim3(24, 24, 12), tb, 0, stream>>>(wk, wAll + 589824, 768, 768, dd, LW);
    transpose_convert<<<dim3(24, 24, 12), tb, 0, stream>>>(wv, wAll + 1179648, 768, 768, dd, LW);
    transpose_convert<<<dim3(24, 24, 12), tb, 0, stream>>>(wo, wAll + 1769472, 768, 768, dd, LW);
    transpose_convert<<<dim3(96, 24, 12), tb, 0, stream>>>(w1, wAll + 2359296, 768, 3072,
                                                           (size_t)768 * 3072, LW);
    transpose_convert<<<dim3(24, 96, 12), tb, 0, stream>>>(w2, wAll + 4718592, 3072, 768,
                                                           (size_t)3072 * 768, LW);
  }
  embed_kernel<<<4096, 256, 0, stream>>>(idx, wte, wpe, x);

  for (int l = 0; l < 12; ++l) {
    const short *pQKV, *pWO, *pW1, *pW2;
    if (big) {
      short* wl = wAll + (size_t)l * LW;
      pQKV = wl;
      pWO = wl + 1769472;
      pW1 = wl + 2359296;
      pW2 = wl + 4718592;
    } else {
      transpose_convert<<<dim3(24, 24, 1), tb, 0, stream>>>(wq + l * dd, wqkvT, 768, 768, 0, 0);
      transpose_convert<<<dim3(24, 24, 1), tb, 0, stream>>>(wk + l * dd, wqkvT + dd, 768, 768, 0, 0);
      transpose_convert<<<dim3(24, 24, 1), tb, 0, stream>>>(wv + l * dd, wqkvT + 2 * dd, 768, 768, 0, 0);
      transpose_convert<<<dim3(24, 24, 1), tb, 0, stream>>>(wo + l * dd, woT, 768, 768, 0, 0);
      transpose_convert<<<dim3(96, 24, 1), tb, 0, stream>>>(w1 + (size_t)l * 768 * 3072, w1T, 768, 3072, 0, 0);
      transpose_convert<<<dim3(24, 96, 1), tb, 0, stream>>>(w2 + (size_t)l * 3072 * 768, w2T, 3072, 768, 0, 0);
      pQKV = wqkvT; pWO = woT; pW1 = w1T; pW2 = w2T;
    }

    ln_kernel<<<4096, 256, 0, stream>>>(x, ln1_g + l * 768, ln1_b + l * 768, h);
    gemm_kernel<EPI_QKV><<<dim3(32, 18), 256, 0, stream>>>(
        h, pQKV, 768, bq + l * 768, bk + l * 768, bv + l * 768, nullptr, qb, kb, vtb);
    attn_kernel<<<dim3(48, 16), 256, 0, stream>>>(qb, kb, vtb, ob);
    gemm_kernel<EPI_RESID><<<dim3(32, 6), 256, 0, stream>>>(
        ob, pWO, 768, bo + l * 768, nullptr, nullptr, x, nullptr, nullptr, nullptr);
    ln_kernel<<<4096, 256, 0, stream>>>(x, ln2_g + l * 768, ln2_b + l * 768, h);
    gemm_kernel<EPI_GELU><<<dim3(32, 24), 256, 0, stream>>>(
        h, pW1, 768, b1 + l * 3072, nullptr, nullptr, nullptr, ff, nullptr, nullptr);
    gemm_kernel<EPI_RESID><<<dim3(32, 6), 256, 0, stream>>>(
        ff, pW2, 3072, b2 + l * 768, nullptr, nullptr, x, nullptr, nullptr, nullptr);
  }

  ln_kernel<<<4096, 256, 0, stream>>>(x, lnf_g, lnf_b, h);
  gemm_lm_kernel<<<dim3(16, 393), 512, 0, stream>>>(h, lmT, out);
}

// Round 5
// 3386.369 us; speedup vs baseline: 1.2440x; 1.1096x over previous
//
#include <hip/hip_runtime.h>
#include <hip/hip_bf16.h>

typedef __attribute__((ext_vector_type(8))) short short8;
typedef __attribute__((ext_vector_type(4))) float floatx4;

#define GLD16(g, l) __builtin_amdgcn_global_load_lds( \
    (__attribute__((address_space(1))) void*)(g),      \
    (__attribute__((address_space(3))) void*)(l), 16, 0, 0)

#define MFMA_BF16(a, b, c) __builtin_amdgcn_mfma_f32_16x16x32_bf16((a), (b), (c), 0, 0, 0)

__device__ __forceinline__ short f2bf(float f) {
  union { __hip_bfloat16 h; short s; } u;
  u.h = __float2bfloat16(f);
  return u.s;
}

// ---------------------------------------------------------------------------
// transpose + fp32->bf16 convert:  in fp32 [K][N] -> out bf16 [Npad][K]
// ---------------------------------------------------------------------------
__global__ __launch_bounds__(256)
void transpose_convert(const float* __restrict__ in, short* __restrict__ out,
                       const int K, const int N, const size_t inStride,
                       const size_t outStride) {
  in += blockIdx.z * inStride;
  out += blockIdx.z * outStride;
  __shared__ float tile[32][33];
  const int n0 = blockIdx.x * 32;
  const int k0 = blockIdx.y * 32;
  const int tx = threadIdx.x;
  const int ty = threadIdx.y;
#pragma unroll
  for (int i = 0; i < 4; ++i) {
    const int kk = ty + i * 8;
    const int nn = n0 + tx;
    tile[kk][tx] = (nn < N) ? in[(size_t)(k0 + kk) * N + nn] : 0.f;
  }
  __syncthreads();
#pragma unroll
  for (int i = 0; i < 4; ++i) {
    const int nn = ty + i * 8;
    out[(size_t)(n0 + nn) * K + k0 + tx] = f2bf(tile[tx][nn]);
  }
}

// ---------------------------------------------------------------------------
__global__ __launch_bounds__(256)
void embed_kernel(const int* __restrict__ idx, const float* __restrict__ wte,
                  const float* __restrict__ wpe, float* __restrict__ x) {
  const int row = blockIdx.x;
  const int tok = idx[row];
  const int s = row & 1023;
  const float* wt = wte + (size_t)tok * 768;
  const float* wp = wpe + (size_t)s * 768;
  float* xr = x + (size_t)row * 768;
  for (int c = threadIdx.x; c < 768; c += 256) xr[c] = wt[c] + wp[c];
}

// ---------------------------------------------------------------------------
__global__ __launch_bounds__(256)
void ln_kernel(const float* __restrict__ x, const float* __restrict__ g,
               const float* __restrict__ b, short* __restrict__ out) {
  const int row = blockIdx.x;
  const int t = threadIdx.x;
  const int wv = t >> 6, lane = t & 63;
  const float* xr = x + (size_t)row * 768;
  const float v0 = xr[t], v1 = xr[t + 256], v2 = xr[t + 512];
  __shared__ float red[4];
  float s = v0 + v1 + v2;
#pragma unroll
  for (int m = 1; m < 64; m <<= 1) s += __shfl_xor(s, m);
  if (lane == 0) red[wv] = s;
  __syncthreads();
  const float mean = (red[0] + red[1] + red[2] + red[3]) * (1.0f / 768.0f);
  __syncthreads();
  const float d0 = v0 - mean, d1 = v1 - mean, d2 = v2 - mean;
  float q = d0 * d0 + d1 * d1 + d2 * d2;
#pragma unroll
  for (int m = 1; m < 64; m <<= 1) q += __shfl_xor(q, m);
  if (lane == 0) red[wv] = q;
  __syncthreads();
  const float var = (red[0] + red[1] + red[2] + red[3]) * (1.0f / 768.0f);
  const float inv = rsqrtf(var + 1e-5f);
  short* orow = out + (size_t)row * 768;
  orow[t] = f2bf(d0 * inv * g[t] + b[t]);
  orow[t + 256] = f2bf(d1 * inv * g[t + 256] + b[t + 256]);
  orow[t + 512] = f2bf(d2 * inv * g[t + 512] + b[t + 512]);
}

// ---------------------------------------------------------------------------
// Layer GEMM: BMx64 tile, BK=32, 256 threads = 4 waves (2Mx2N), 2-phase dbuf.
// BM=128 for wide-N GEMMs (QKV/MLP1), BM=64 for N=768 GEMMs (proj/MLP2) to
// raise blocks/CU (occupancy was the binding constraint at 128x128).
// ---------------------------------------------------------------------------
enum { EPI_QKV = 0, EPI_RESID = 1, EPI_GELU = 2 };

template <int BM, int EPI>
__global__ __launch_bounds__(256)
void gemm_kernel(const short* __restrict__ A, const short* __restrict__ Bt,
                 const int K,
                 const float* __restrict__ bias0, const float* __restrict__ bias1,
                 const float* __restrict__ bias2, float* __restrict__ fout,
                 short* __restrict__ bout0, short* __restrict__ bout1,
                 short* __restrict__ bout2) {
  constexpr int MF = BM / 32;       // m-frags per wave
  constexpr int AR = BM / 64;       // A staging rounds (256 thr x 16B)
  __shared__ short sA[2][BM * 32];
  __shared__ short sB[2][64 * 32];
  const int tid = threadIdx.x;
  const int wv = tid >> 6;
  const int lane = tid & 63;
  const int lrow = lane & 15;
  const int lk8 = lane >> 4;
  const int m0 = blockIdx.x * BM;
  const int n0 = blockIdx.y * 64;
  const int wm = (wv >> 1) * (BM / 2);
  const int wn = (wv & 1) * 32;

  floatx4 acc[MF][2];
#pragma unroll
  for (int m = 0; m < MF; ++m)
#pragma unroll
    for (int n = 0; n < 2; ++n) acc[m][n] = {0.f, 0.f, 0.f, 0.f};

  const short* Ab = A + (size_t)m0 * K;
  const short* Bb = Bt + (size_t)n0 * K;

  const int nk = K >> 5;
  // prologue: stage tile 0 into buffer 0
#pragma unroll
  for (int i = 0; i < AR; ++i) {
    const int e = (i * 256 + tid) * 8;
    GLD16(Ab + (size_t)(e >> 5) * K + (e & 31), sA[0] + i * 2048 + wv * 512);
  }
  {
    const int e = tid * 8;
    GLD16(Bb + (size_t)(e >> 5) * K + (e & 31), sB[0] + wv * 512);
  }
  __syncthreads();

  int cur = 0;
  for (int kt = 0; kt < nk; ++kt) {
    if (kt + 1 < nk) {
      const int kb = (kt + 1) << 5;
#pragma unroll
      for (int i = 0; i < AR; ++i) {
        const int e = (i * 256 + tid) * 8;
        GLD16(Ab + (size_t)(e >> 5) * K + kb + (e & 31),
              sA[cur ^ 1] + i * 2048 + wv * 512);
      }
      const int e = tid * 8;
      GLD16(Bb + (size_t)(e >> 5) * K + kb + (e & 31), sB[cur ^ 1] + wv * 512);
    }
    short8 af[MF], bfv[2];
#pragma unroll
    for (int m = 0; m < MF; ++m)
      af[m] = *(const short8*)(sA[cur] + (wm + m * 16 + lrow) * 32 + lk8 * 8);
#pragma unroll
    for (int n = 0; n < 2; ++n)
      bfv[n] = *(const short8*)(sB[cur] + (wn + n * 16 + lrow) * 32 + lk8 * 8);
#pragma unroll
    for (int m = 0; m < MF; ++m)
#pragma unroll
      for (int n = 0; n < 2; ++n)
        acc[m][n] = MFMA_BF16(af[m], bfv[n], acc[m][n]);
    __syncthreads();
    cur ^= 1;
  }

#pragma unroll
  for (int m = 0; m < MF; ++m) {
#pragma unroll
    for (int n = 0; n < 2; ++n) {
#pragma unroll
      for (int r = 0; r < 4; ++r) {
        const float v = acc[m][n][r];
        const int gm = m0 + wm + m * 16 + lk8 * 4 + r;
        const int gn = n0 + wn + n * 16 + lrow;
        if (EPI == EPI_QKV) {
          const int sec = (gn >= 1536) ? 2 : (gn >= 768 ? 1 : 0);
          const int nn = gn - sec * 768;
          const int hh = nn >> 6, dh = nn & 63;
          const int bb = gm >> 10, srow = gm & 1023;
          if (sec == 0) {
            bout0[(((size_t)(bb * 12 + hh) * 1024 + srow) << 6) + dh] =
                f2bf((v + bias0[nn]) * 0.125f);
          } else if (sec == 1) {
            bout1[(((size_t)(bb * 12 + hh) * 1024 + srow) << 6) + dh] =
                f2bf(v + bias1[nn]);
          } else {
            bout2[(((size_t)(bb * 12 + hh) * 64 + dh) << 10) + srow] =
                f2bf(v + bias2[nn]);
          }
        } else if (EPI == EPI_RESID) {
          float* xp = fout + (size_t)gm * 768 + gn;
          *xp = *xp + v + bias0[gn];
        } else {  // EPI_GELU
          const float tt = v + bias0[gn];
          const float gl = 0.5f * tt * (1.f + erff(tt * 0.70710678118654752f));
          bout0[(size_t)gm * 3072 + gn] = f2bf(gl);
        }
      }
    }
  }
}

// ---------------------------------------------------------------------------
// LM-head GEMM: 256x128 tile, BK=32, 512 threads = 8 waves, double-buffered.
// Natural dispatch order (bx%8 pins A-panels per XCD; cross-XCD temporal
// alignment on B through L3 — measured r2 vs r3).
// ---------------------------------------------------------------------------
__global__ __launch_bounds__(512)
void gemm_lm_kernel(const short* __restrict__ A, const short* __restrict__ Bt,
                    float* __restrict__ fout) {
  __shared__ short sA[2][256 * 32];
  __shared__ short sB[2][128 * 32];
  const int K = 768;
  const int tid = threadIdx.x;
  const int wv = tid >> 6;
  const int lane = tid & 63;
  const int lrow = lane & 15;
  const int lk8 = lane >> 4;
  const int m0 = blockIdx.x * 256;
  const int n0 = blockIdx.y * 128;
  const int wm = (wv >> 1) * 64;
  const int wn = (wv & 1) * 64;

  floatx4 acc[4][4];
#pragma unroll
  for (int m = 0; m < 4; ++m)
#pragma unroll
    for (int n = 0; n < 4; ++n) acc[m][n] = {0.f, 0.f, 0.f, 0.f};

  const int rA0 = tid >> 2, cA0 = (tid & 3) * 8;
  const int rA1 = 128 + (tid >> 2), cA1 = (tid & 3) * 8;
  const int rB = tid >> 2, cB = (tid & 3) * 8;

  const short* Ab = A + (size_t)m0 * K;
  const short* Bb = Bt + (size_t)n0 * K;

  GLD16(Ab + (size_t)rA0 * K + cA0, sA[0] + wv * 512);
  GLD16(Ab + (size_t)rA1 * K + cA1, sA[0] + 4096 + wv * 512);
  GLD16(Bb + (size_t)rB * K + cB, sB[0] + wv * 512);
  __syncthreads();

  int cur = 0;
  for (int kt = 0; kt < 24; ++kt) {
    if (kt + 1 < 24) {
      const int kb = (kt + 1) << 5;
      GLD16(Ab + (size_t)rA0 * K + kb + cA0, sA[cur ^ 1] + wv * 512);
      GLD16(Ab + (size_t)rA1 * K + kb + cA1, sA[cur ^ 1] + 4096 + wv * 512);
      GLD16(Bb + (size_t)rB * K + kb + cB, sB[cur ^ 1] + wv * 512);
    }
    short8 af[4], bfv[4];
#pragma unroll
    for (int m = 0; m < 4; ++m)
      af[m] = *(const short8*)(sA[cur] + (wm + m * 16 + lrow) * 32 + lk8 * 8);
#pragma unroll
    for (int n = 0; n < 4; ++n)
      bfv[n] = *(const short8*)(sB[cur] + (wn + n * 16 + lrow) * 32 + lk8 * 8);
#pragma unroll
    for (int m = 0; m < 4; ++m)
#pragma unroll
      for (int n = 0; n < 4; ++n)
        acc[m][n] = MFMA_BF16(af[m], bfv[n], acc[m][n]);
    __syncthreads();
    cur ^= 1;
  }

#pragma unroll
  for (int m = 0; m < 4; ++m)
#pragma unroll
    for (int n = 0; n < 4; ++n)
#pragma unroll
      for (int r = 0; r < 4; ++r) {
        const int gm = m0 + wm + m * 16 + lk8 * 4 + r;
        const int gn = n0 + wn + n * 16 + lrow;
        if (gn < 50257) fout[(size_t)gm * 50257 + gn] = acc[m][n][r];
      }
}

// ---------------------------------------------------------------------------
// flash attention (causal), LDS-staged K/V, heavy q-blocks first.
// q,k [48][1024][64] bf16 (q pre-scaled 1/8), vt [48][64][1024] bf16
// -> o [4096][768] bf16. grid (48,16), block 256.
// ---------------------------------------------------------------------------
__global__ __launch_bounds__(256)
void attn_kernel(const short* __restrict__ q, const short* __restrict__ k,
                 const short* __restrict__ vt, short* __restrict__ o) {
  __shared__ short sK[64 * 64];
  __shared__ short sV[64 * 64];
  __shared__ short sP[4][16 * 64];
  const int bh = blockIdx.x;
  const int qi = 15 - blockIdx.y;
  const int tid = threadIdx.x;
  const int wv = tid >> 6, lane = tid & 63;
  const int lrow = lane & 15, lk8 = lane >> 4;
  const int q0 = qi * 64;

  const short* qg = q + ((size_t)(bh * 1024 + q0 + wv * 16 + lrow)) * 64 + lk8 * 8;
  const short8 qf0 = *(const short8*)qg;
  const short8 qf1 = *(const short8*)(qg + 32);

  float m_run[4], lsum[4];
  floatx4 accO[4];
#pragma unroll
  for (int r = 0; r < 4; ++r) { m_run[r] = -1e30f; lsum[r] = 0.f; }
#pragma unroll
  for (int n = 0; n < 4; ++n) accO[n] = {0.f, 0.f, 0.f, 0.f};

  for (int t = 0; t <= qi; ++t) {
    const int k0 = t * 64;
#pragma unroll
    for (int i = 0; i < 2; ++i) {
      const int e = (i * 256 + tid) * 8;
      const int r = e >> 6, cc = e & 63;
      const int su = ((cc >> 3) ^ (r & 7)) << 3;
      *(short8*)(sK + r * 64 + su) =
          *(const short8*)(k + ((size_t)(bh * 1024 + k0 + r)) * 64 + cc);
      *(short8*)(sV + r * 64 + su) =
          *(const short8*)(vt + ((size_t)(bh * 64 + r)) * 1024 + k0 + cc);
    }
    __syncthreads();

    floatx4 accS[4];
#pragma unroll
    for (int n = 0; n < 4; ++n) accS[n] = {0.f, 0.f, 0.f, 0.f};
#pragma unroll
    for (int ks = 0; ks < 2; ++ks) {
      const short8 qf = ks ? qf1 : qf0;
      const int u = lk8 + ks * 4;
#pragma unroll
      for (int n = 0; n < 4; ++n) {
        const int key = n * 16 + lrow;
        const short8 kf = *(const short8*)(sK + key * 64 + ((u ^ (key & 7)) << 3));
        accS[n] = MFMA_BF16(qf, kf, accS[n]);
      }
    }

#pragma unroll
    for (int r = 0; r < 4; ++r) {
      const int qrow = q0 + wv * 16 + lk8 * 4 + r;
      float sv[4];
      float mx = -1e30f;
#pragma unroll
      for (int n = 0; n < 4; ++n) {
        float s = accS[n][r];
        const int key = k0 + n * 16 + lrow;
        s = (key > qrow) ? -1e30f : s;
        sv[n] = s;
        mx = fmaxf(mx, s);
      }
#pragma unroll
      for (int m = 1; m < 16; m <<= 1) mx = fmaxf(mx, __shfl_xor(mx, m));
      const float mnew = fmaxf(m_run[r], mx);
      const float sf = __expf(m_run[r] - mnew);
      m_run[r] = mnew;
      float rs = 0.f;
      const int prow = lk8 * 4 + r;
#pragma unroll
      for (int n = 0; n < 4; ++n) {
        const float pv = __expf(sv[n] - mnew);
        rs += pv;
        const int col = n * 16 + lrow;
        sP[wv][prow * 64 + (((col >> 3) ^ (prow & 7)) << 3) + (col & 7)] = f2bf(pv);
      }
#pragma unroll
      for (int m = 1; m < 16; m <<= 1) rs += __shfl_xor(rs, m);
      lsum[r] = lsum[r] * sf + rs;
#pragma unroll
      for (int n = 0; n < 4; ++n) accO[n][r] *= sf;
    }

#pragma unroll
    for (int ks = 0; ks < 2; ++ks) {
      const int u = lk8 + ks * 4;
      const short8 pf =
          *(const short8*)(&sP[wv][lrow * 64 + ((u ^ (lrow & 7)) << 3)]);
#pragma unroll
      for (int n = 0; n < 4; ++n) {
        const int dh = n * 16 + lrow;
        const short8 vf = *(const short8*)(sV + dh * 64 + ((u ^ (dh & 7)) << 3));
        accO[n] = MFMA_BF16(pf, vf, accO[n]);
      }
    }
    __syncthreads();
  }

  const int bb = bh / 12, hh = bh % 12;
#pragma unroll
  for (int n = 0; n < 4; ++n)
#pragma unroll
    for (int r = 0; r < 4; ++r) {
      const int row = q0 + wv * 16 + lk8 * 4 + r;
      const float ov = accO[n][r] / lsum[r];
      o[((size_t)(bb * 1024 + row)) * 768 + hh * 64 + n * 16 + lrow] = f2bf(ov);
    }
}

// ---------------------------------------------------------------------------
extern "C" void kernel_launch(void* const* d_in, const int* in_sizes, int n_in,
                              void* d_out, int out_size, void* d_ws, size_t ws_size,
                              hipStream_t stream) {
  const int* idx = (const int*)d_in[0];
  const float* wte = (const float*)d_in[1];
  const float* wpe = (const float*)d_in[2];
  const float* ln1_g = (const float*)d_in[3];
  const float* ln1_b = (const float*)d_in[4];
  const float* wq = (const float*)d_in[5];
  const float* bq = (const float*)d_in[6];
  const float* wk = (const float*)d_in[7];
  const float* bk = (const float*)d_in[8];
  const float* wv = (const float*)d_in[9];
  const float* bv = (const float*)d_in[10];
  const float* wo = (const float*)d_in[11];
  const float* bo = (const float*)d_in[12];
  const float* ln2_g = (const float*)d_in[13];
  const float* ln2_b = (const float*)d_in[14];
  const float* w1 = (const float*)d_in[15];
  const float* b1 = (const float*)d_in[16];
  const float* w2 = (const float*)d_in[17];
  const float* b2 = (const float*)d_in[18];
  const float* lnf_g = (const float*)d_in[19];
  const float* lnf_b = (const float*)d_in[20];
  const float* lm_w = (const float*)d_in[21];
  float* out = (float*)d_out;

  char* base = (char*)d_ws;
  size_t off = 0;
  auto alloc = [&](size_t bytes) {
    char* r = base + off;
    off = (off + bytes + 255) & ~(size_t)255;
    return r;
  };
  short* lmT = (short*)alloc((size_t)50304 * 768 * 2);
  float* x = (float*)alloc((size_t)4096 * 768 * 4);
  short* h = (short*)alloc((size_t)4096 * 768 * 2);
  short* qb = (short*)alloc((size_t)4096 * 768 * 2);
  short* kb = (short*)alloc((size_t)4096 * 768 * 2);
  short* vtb = (short*)alloc((size_t)4096 * 768 * 2);
  short* ob = (short*)alloc((size_t)4096 * 768 * 2);
  short* ff = (short*)alloc((size_t)4096 * 3072 * 2);

  const size_t LW = 7077888;  // elements per layer weight block
  const size_t dd = (size_t)768 * 768;
  const bool big = (off + (size_t)12 * LW * 2 + 256 <= ws_size);
  short* wAll = nullptr;
  short *wqkvT = nullptr, *woT = nullptr, *w1T = nullptr, *w2T = nullptr;
  if (big) {
    wAll = (short*)alloc((size_t)12 * LW * 2);
  } else {
    wqkvT = (short*)alloc((size_t)2304 * 768 * 2);
    woT = (short*)alloc((size_t)768 * 768 * 2);
    w1T = (short*)alloc((size_t)3072 * 768 * 2);
    w2T = (short*)alloc((size_t)768 * 3072 * 2);
    if (off > ws_size) return;
  }

  const dim3 tb(32, 8);
  transpose_convert<<<dim3(1572, 24, 1), tb, 0, stream>>>(lm_w, lmT, 768, 50257, 0, 0);
  if (big) {
    transpose_convert<<<dim3(24, 24, 12), tb, 0, stream>>>(wq, wAll + 0, 768, 768, dd, LW);
    transpose_convert<<<dim3(24, 24, 12), tb, 0, stream>>>(wk, wAll + 589824, 768, 768, dd, LW);
    transpose_convert<<<dim3(24, 24, 12), tb, 0, stream>>>(wv, wAll + 1179648, 768, 768, dd, LW);
    transpose_convert<<<dim3(24, 24, 12), tb, 0, stream>>>(wo, wAll + 1769472, 768, 768, dd, LW);
    transpose_convert<<<dim3(96, 24, 12), tb, 0, stream>>>(w1, wAll + 2359296, 768, 3072,
                                                           (size_t)768 * 3072, LW);
    transpose_convert<<<dim3(24, 96, 12), tb, 0, stream>>>(w2, wAll + 4718592, 3072, 768,
                                                           (size_t)3072 * 768, LW);
  }
  embed_kernel<<<4096, 256, 0, stream>>>(idx, wte, wpe, x);

  for (int l = 0; l < 12; ++l) {
    const short *pQKV, *pWO, *pW1, *pW2;
    if (big) {
      short* wl = wAll + (size_t)l * LW;
      pQKV = wl;
      pWO = wl + 1769472;
      pW1 = wl + 2359296;
      pW2 = wl + 4718592;
    } else {
      transpose_convert<<<dim3(24, 24, 1), tb, 0, stream>>>(wq + l * dd, wqkvT, 768, 768, 0, 0);
      transpose_convert<<<dim3(24, 24, 1), tb, 0, stream>>>(wk + l * dd, wqkvT + dd, 768, 768, 0, 0);
      transpose_convert<<<dim3(24, 24, 1), tb, 0, stream>>>(wv + l * dd, wqkvT + 2 * dd, 768, 768, 0, 0);
      transpose_convert<<<dim3(24, 24, 1), tb, 0, stream>>>(wo + l * dd, woT, 768, 768, 0, 0);
      transpose_convert<<<dim3(96, 24, 1), tb, 0, stream>>>(w1 + (size_t)l * 768 * 3072, w1T, 768, 3072, 0, 0);
      transpose_convert<<<dim3(24, 96, 1), tb, 0, stream>>>(w2 + (size_t)l * 3072 * 768, w2T, 3072, 768, 0, 0);
      pQKV = wqkvT; pWO = woT; pW1 = w1T; pW2 = w2T;
    }

    ln_kernel<<<4096, 256, 0, stream>>>(x, ln1_g + l * 768, ln1_b + l * 768, h);
    gemm_kernel<128, EPI_QKV><<<dim3(32, 36), 256, 0, stream>>>(
        h, pQKV, 768, bq + l * 768, bk + l * 768, bv + l * 768, nullptr, qb, kb, vtb);
    attn_kernel<<<dim3(48, 16), 256, 0, stream>>>(qb, kb, vtb, ob);
    gemm_kernel<64, EPI_RESID><<<dim3(64, 12), 256, 0, stream>>>(
        ob, pWO, 768, bo + l * 768, nullptr, nullptr, x, nullptr, nullptr, nullptr);
    ln_kernel<<<4096, 256, 0, stream>>>(x, ln2_g + l * 768, ln2_b + l * 768, h);
    gemm_kernel<128, EPI_GELU><<<dim3(32, 48), 256, 0, stream>>>(
        h, pW1, 768, b1 + l * 3072, nullptr, nullptr, nullptr, ff, nullptr, nullptr);
    gemm_kernel<64, EPI_RESID><<<dim3(64, 12), 256, 0, stream>>>(
        ff, pW2, 3072, b2 + l * 768, nullptr, nullptr, x, nullptr, nullptr, nullptr);
  }

  ln_kernel<<<4096, 256, 0, stream>>>(x, lnf_g, lnf_b, h);
  gemm_lm_kernel<<<dim3(16, 393), 512, 0, stream>>>(h, lmT, out);
}

// Round 6
// 3270.917 us; speedup vs baseline: 1.2879x; 1.0353x over previous
//
#include <hip/hip_runtime.h>
#include <hip/hip_bf16.h>

typedef __attribute__((ext_vector_type(8))) short short8;
typedef __attribute__((ext_vector_type(4))) float floatx4;

#define GLD16(g, l) __builtin_amdgcn_global_load_lds( \
    (__attribute__((address_space(1))) void*)(g),      \
    (__attribute__((address_space(3))) void*)(l), 16, 0, 0)

#define MFMA_BF16(a, b, c) __builtin_amdgcn_mfma_f32_16x16x32_bf16((a), (b), (c), 0, 0, 0)

__device__ __forceinline__ short f2bf(float f) {
  union { __hip_bfloat16 h; short s; } u;
  u.h = __float2bfloat16(f);
  return u.s;
}

// ---------------------------------------------------------------------------
// transpose + fp32->bf16 convert:  in fp32 [K][N] -> out bf16 [Npad][K]
// ---------------------------------------------------------------------------
__global__ __launch_bounds__(256)
void transpose_convert(const float* __restrict__ in, short* __restrict__ out,
                       const int K, const int N, const size_t inStride,
                       const size_t outStride) {
  in += blockIdx.z * inStride;
  out += blockIdx.z * outStride;
  __shared__ float tile[32][33];
  const int n0 = blockIdx.x * 32;
  const int k0 = blockIdx.y * 32;
  const int tx = threadIdx.x;
  const int ty = threadIdx.y;
#pragma unroll
  for (int i = 0; i < 4; ++i) {
    const int kk = ty + i * 8;
    const int nn = n0 + tx;
    tile[kk][tx] = (nn < N) ? in[(size_t)(k0 + kk) * N + nn] : 0.f;
  }
  __syncthreads();
#pragma unroll
  for (int i = 0; i < 4; ++i) {
    const int nn = ty + i * 8;
    out[(size_t)(n0 + nn) * K + k0 + tx] = f2bf(tile[tx][nn]);
  }
}

// ---------------------------------------------------------------------------
__global__ __launch_bounds__(256)
void embed_kernel(const int* __restrict__ idx, const float* __restrict__ wte,
                  const float* __restrict__ wpe, float* __restrict__ x) {
  const int row = blockIdx.x;
  const int tok = idx[row];
  const int s = row & 1023;
  const float* wt = wte + (size_t)tok * 768;
  const float* wp = wpe + (size_t)s * 768;
  float* xr = x + (size_t)row * 768;
  for (int c = threadIdx.x; c < 768; c += 256) xr[c] = wt[c] + wp[c];
}

// ---------------------------------------------------------------------------
__global__ __launch_bounds__(256)
void ln_kernel(const float* __restrict__ x, const float* __restrict__ g,
               const float* __restrict__ b, short* __restrict__ out) {
  const int row = blockIdx.x;
  const int t = threadIdx.x;
  const int wv = t >> 6, lane = t & 63;
  const float* xr = x + (size_t)row * 768;
  const float v0 = xr[t], v1 = xr[t + 256], v2 = xr[t + 512];
  __shared__ float red[4];
  float s = v0 + v1 + v2;
#pragma unroll
  for (int m = 1; m < 64; m <<= 1) s += __shfl_xor(s, m);
  if (lane == 0) red[wv] = s;
  __syncthreads();
  const float mean = (red[0] + red[1] + red[2] + red[3]) * (1.0f / 768.0f);
  __syncthreads();
  const float d0 = v0 - mean, d1 = v1 - mean, d2 = v2 - mean;
  float q = d0 * d0 + d1 * d1 + d2 * d2;
#pragma unroll
  for (int m = 1; m < 64; m <<= 1) q += __shfl_xor(q, m);
  if (lane == 0) red[wv] = q;
  __syncthreads();
  const float var = (red[0] + red[1] + red[2] + red[3]) * (1.0f / 768.0f);
  const float inv = rsqrtf(var + 1e-5f);
  short* orow = out + (size_t)row * 768;
  orow[t] = f2bf(d0 * inv * g[t] + b[t]);
  orow[t + 256] = f2bf(d1 * inv * g[t + 256] + b[t + 256]);
  orow[t + 512] = f2bf(d2 * inv * g[t + 512] + b[t + 512]);
}

// ---------------------------------------------------------------------------
// GEMM: BMxBN tile, BK=64 (128B LDS rows span all 32 banks), unit-XOR swizzle
// phys_unit = u ^ (row&7) applied on the per-lane GLOBAL source address
// (LDS dest linear for global_load_lds) and on the ds_read address -> 2-way
// (free) bank conflicts instead of 8-way at BK=32. 256 threads = 4 waves,
// double-buffered, one barrier per K-64 step.
// ---------------------------------------------------------------------------
enum { EPI_QKV = 0, EPI_RESID = 1, EPI_GELU = 2, EPI_LM = 3 };

template <int BM, int BN>
__device__ __forceinline__ void stage_tiles(const short* __restrict__ Ab,
                                            const short* __restrict__ Bb,
                                            const int K, const int kb,
                                            short* pa, short* pb,
                                            const int tid, const int wv) {
#pragma unroll
  for (int i = 0; i < BM / 32; ++i) {
    const int p = i * 256 + tid;
    const int rr = p >> 3, up = p & 7;
    GLD16(Ab + (size_t)rr * K + kb + ((up ^ (rr & 7)) << 3),
          pa + (i * 256 + wv * 64) * 8);
  }
#pragma unroll
  for (int i = 0; i < BN / 32; ++i) {
    const int p = i * 256 + tid;
    const int rr = p >> 3, up = p & 7;
    GLD16(Bb + (size_t)rr * K + kb + ((up ^ (rr & 7)) << 3),
          pb + (i * 256 + wv * 64) * 8);
  }
}

template <int BM, int BN, int EPI>
__global__ __launch_bounds__(256)
void gemm_kernel(const short* __restrict__ A, const short* __restrict__ Bt,
                 const int K,
                 const float* __restrict__ bias0, const float* __restrict__ bias1,
                 const float* __restrict__ bias2, float* __restrict__ fout,
                 short* __restrict__ bout0, short* __restrict__ bout1,
                 short* __restrict__ bout2) {
  constexpr int MF = BM / 32;
  constexpr int NF = BN / 32;
  __shared__ short sA[2][BM * 64];
  __shared__ short sB[2][BN * 64];
  const int tid = threadIdx.x;
  const int wv = tid >> 6;
  const int lane = tid & 63;
  const int lrow = lane & 15;
  const int lk8 = lane >> 4;
  const int m0 = blockIdx.x * BM;
  const int n0 = blockIdx.y * BN;
  const int wm = (wv >> 1) * (BM / 2);
  const int wn = (wv & 1) * (BN / 2);

  floatx4 acc[MF][NF];
#pragma unroll
  for (int m = 0; m < MF; ++m)
#pragma unroll
    for (int n = 0; n < NF; ++n) acc[m][n] = {0.f, 0.f, 0.f, 0.f};

  const short* Ab = A + (size_t)m0 * K;
  const short* Bb = Bt + (size_t)n0 * K;

  const int nk = K >> 6;
  stage_tiles<BM, BN>(Ab, Bb, K, 0, sA[0], sB[0], tid, wv);
  __syncthreads();

  int cur = 0;
  for (int kt = 0; kt < nk; ++kt) {
    if (kt + 1 < nk)
      stage_tiles<BM, BN>(Ab, Bb, K, (kt + 1) << 6, sA[cur ^ 1], sB[cur ^ 1],
                          tid, wv);
    const short* pa = sA[cur];
    const short* pb = sB[cur];
    short8 af[MF][2], bv[NF][2];
#pragma unroll
    for (int m = 0; m < MF; ++m)
#pragma unroll
      for (int ks = 0; ks < 2; ++ks)
        af[m][ks] = *(const short8*)(pa + (wm + m * 16 + lrow) * 64 +
                                     (((ks * 4 + lk8) ^ (lrow & 7)) << 3));
#pragma unroll
    for (int n = 0; n < NF; ++n)
#pragma unroll
      for (int ks = 0; ks < 2; ++ks)
        bv[n][ks] = *(const short8*)(pb + (wn + n * 16 + lrow) * 64 +
                                     (((ks * 4 + lk8) ^ (lrow & 7)) << 3));
#pragma unroll
    for (int m = 0; m < MF; ++m)
#pragma unroll
      for (int n = 0; n < NF; ++n) {
        acc[m][n] = MFMA_BF16(af[m][0], bv[n][0], acc[m][n]);
        acc[m][n] = MFMA_BF16(af[m][1], bv[n][1], acc[m][n]);
      }
    __syncthreads();
    cur ^= 1;
  }

#pragma unroll
  for (int m = 0; m < MF; ++m) {
#pragma unroll
    for (int n = 0; n < NF; ++n) {
#pragma unroll
      for (int r = 0; r < 4; ++r) {
        const float v = acc[m][n][r];
        const int gm = m0 + wm + m * 16 + lk8 * 4 + r;
        const int gn = n0 + wn + n * 16 + lrow;
        if (EPI == EPI_QKV) {
          const int sec = (gn >= 1536) ? 2 : (gn >= 768 ? 1 : 0);
          const int nn = gn - sec * 768;
          const int hh = nn >> 6, dh = nn & 63;
          const int bb = gm >> 10, srow = gm & 1023;
          if (sec == 0) {
            bout0[(((size_t)(bb * 12 + hh) * 1024 + srow) << 6) + dh] =
                f2bf((v + bias0[nn]) * 0.125f);
          } else if (sec == 1) {
            bout1[(((size_t)(bb * 12 + hh) * 1024 + srow) << 6) + dh] =
                f2bf(v + bias1[nn]);
          } else {
            bout2[(((size_t)(bb * 12 + hh) * 64 + dh) << 10) + srow] =
                f2bf(v + bias2[nn]);
          }
        } else if (EPI == EPI_RESID) {
          float* xp = fout + (size_t)gm * 768 + gn;
          *xp = *xp + v + bias0[gn];
        } else if (EPI == EPI_GELU) {
          const float tt = v + bias0[gn];
          const float gl = 0.5f * tt * (1.f + erff(tt * 0.70710678118654752f));
          bout0[(size_t)gm * 3072 + gn] = f2bf(gl);
        } else {  // EPI_LM
          if (gn < 50257) fout[(size_t)gm * 50257 + gn] = v;
        }
      }
    }
  }
}

// ---------------------------------------------------------------------------
// flash attention (causal), LDS-staged K/V, heavy q-blocks first.
// q,k [48][1024][64] bf16 (q pre-scaled 1/8), vt [48][64][1024] bf16
// -> o [4096][768] bf16. grid (48,16), block 256.
// ---------------------------------------------------------------------------
__global__ __launch_bounds__(256)
void attn_kernel(const short* __restrict__ q, const short* __restrict__ k,
                 const short* __restrict__ vt, short* __restrict__ o) {
  __shared__ short sK[64 * 64];
  __shared__ short sV[64 * 64];
  __shared__ short sP[4][16 * 64];
  const int bh = blockIdx.x;
  const int qi = 15 - blockIdx.y;
  const int tid = threadIdx.x;
  const int wv = tid >> 6, lane = tid & 63;
  const int lrow = lane & 15, lk8 = lane >> 4;
  const int q0 = qi * 64;

  const short* qg = q + ((size_t)(bh * 1024 + q0 + wv * 16 + lrow)) * 64 + lk8 * 8;
  const short8 qf0 = *(const short8*)qg;
  const short8 qf1 = *(const short8*)(qg + 32);

  float m_run[4], lsum[4];
  floatx4 accO[4];
#pragma unroll
  for (int r = 0; r < 4; ++r) { m_run[r] = -1e30f; lsum[r] = 0.f; }
#pragma unroll
  for (int n = 0; n < 4; ++n) accO[n] = {0.f, 0.f, 0.f, 0.f};

  for (int t = 0; t <= qi; ++t) {
    const int k0 = t * 64;
#pragma unroll
    for (int i = 0; i < 2; ++i) {
      const int e = (i * 256 + tid) * 8;
      const int r = e >> 6, cc = e & 63;
      const int su = ((cc >> 3) ^ (r & 7)) << 3;
      *(short8*)(sK + r * 64 + su) =
          *(const short8*)(k + ((size_t)(bh * 1024 + k0 + r)) * 64 + cc);
      *(short8*)(sV + r * 64 + su) =
          *(const short8*)(vt + ((size_t)(bh * 64 + r)) * 1024 + k0 + cc);
    }
    __syncthreads();

    floatx4 accS[4];
#pragma unroll
    for (int n = 0; n < 4; ++n) accS[n] = {0.f, 0.f, 0.f, 0.f};
#pragma unroll
    for (int ks = 0; ks < 2; ++ks) {
      const short8 qf = ks ? qf1 : qf0;
      const int u = lk8 + ks * 4;
#pragma unroll
      for (int n = 0; n < 4; ++n) {
        const int key = n * 16 + lrow;
        const short8 kf = *(const short8*)(sK + key * 64 + ((u ^ (key & 7)) << 3));
        accS[n] = MFMA_BF16(qf, kf, accS[n]);
      }
    }

#pragma unroll
    for (int r = 0; r < 4; ++r) {
      const int qrow = q0 + wv * 16 + lk8 * 4 + r;
      float sv[4];
      float mx = -1e30f;
#pragma unroll
      for (int n = 0; n < 4; ++n) {
        float s = accS[n][r];
        const int key = k0 + n * 16 + lrow;
        s = (key > qrow) ? -1e30f : s;
        sv[n] = s;
        mx = fmaxf(mx, s);
      }
#pragma unroll
      for (int m = 1; m < 16; m <<= 1) mx = fmaxf(mx, __shfl_xor(mx, m));
      const float mnew = fmaxf(m_run[r], mx);
      const float sf = __expf(m_run[r] - mnew);
      m_run[r] = mnew;
      float rs = 0.f;
      const int prow = lk8 * 4 + r;
#pragma unroll
      for (int n = 0; n < 4; ++n) {
        const float pv = __expf(sv[n] - mnew);
        rs += pv;
        const int col = n * 16 + lrow;
        sP[wv][prow * 64 + (((col >> 3) ^ (prow & 7)) << 3) + (col & 7)] = f2bf(pv);
      }
#pragma unroll
      for (int m = 1; m < 16; m <<= 1) rs += __shfl_xor(rs, m);
      lsum[r] = lsum[r] * sf + rs;
#pragma unroll
      for (int n = 0; n < 4; ++n) accO[n][r] *= sf;
    }

#pragma unroll
    for (int ks = 0; ks < 2; ++ks) {
      const int u = lk8 + ks * 4;
      const short8 pf =
          *(const short8*)(&sP[wv][lrow * 64 + ((u ^ (lrow & 7)) << 3)]);
#pragma unroll
      for (int n = 0; n < 4; ++n) {
        const int dh = n * 16 + lrow;
        const short8 vf = *(const short8*)(sV + dh * 64 + ((u ^ (dh & 7)) << 3));
        accO[n] = MFMA_BF16(pf, vf, accO[n]);
      }
    }
    __syncthreads();
  }

  const int bb = bh / 12, hh = bh % 12;
#pragma unroll
  for (int n = 0; n < 4; ++n)
#pragma unroll
    for (int r = 0; r < 4; ++r) {
      const int row = q0 + wv * 16 + lk8 * 4 + r;
      const float ov = accO[n][r] / lsum[r];
      o[((size_t)(bb * 1024 + row)) * 768 + hh * 64 + n * 16 + lrow] = f2bf(ov);
    }
}

// ---------------------------------------------------------------------------
extern "C" void kernel_launch(void* const* d_in, const int* in_sizes, int n_in,
                              void* d_out, int out_size, void* d_ws, size_t ws_size,
                              hipStream_t stream) {
  const int* idx = (const int*)d_in[0];
  const float* wte = (const float*)d_in[1];
  const float* wpe = (const float*)d_in[2];
  const float* ln1_g = (const float*)d_in[3];
  const float* ln1_b = (const float*)d_in[4];
  const float* wq = (const float*)d_in[5];
  const float* bq = (const float*)d_in[6];
  const float* wk = (const float*)d_in[7];
  const float* bk = (const float*)d_in[8];
  const float* wv = (const float*)d_in[9];
  const float* bv = (const float*)d_in[10];
  const float* wo = (const float*)d_in[11];
  const float* bo = (const float*)d_in[12];
  const float* ln2_g = (const float*)d_in[13];
  const float* ln2_b = (const float*)d_in[14];
  const float* w1 = (const float*)d_in[15];
  const float* b1 = (const float*)d_in[16];
  const float* w2 = (const float*)d_in[17];
  const float* b2 = (const float*)d_in[18];
  const float* lnf_g = (const float*)d_in[19];
  const float* lnf_b = (const float*)d_in[20];
  const float* lm_w = (const float*)d_in[21];
  float* out = (float*)d_out;

  char* base = (char*)d_ws;
  size_t off = 0;
  auto alloc = [&](size_t bytes) {
    char* r = base + off;
    off = (off + bytes + 255) & ~(size_t)255;
    return r;
  };
  short* lmT = (short*)alloc((size_t)50304 * 768 * 2);
  float* x = (float*)alloc((size_t)4096 * 768 * 4);
  short* h = (short*)alloc((size_t)4096 * 768 * 2);
  short* qb = (short*)alloc((size_t)4096 * 768 * 2);
  short* kb = (short*)alloc((size_t)4096 * 768 * 2);
  short* vtb = (short*)alloc((size_t)4096 * 768 * 2);
  short* ob = (short*)alloc((size_t)4096 * 768 * 2);
  short* ff = (short*)alloc((size_t)4096 * 3072 * 2);

  const size_t LW = 7077888;  // elements per layer weight block
  const size_t dd = (size_t)768 * 768;
  const bool big = (off + (size_t)12 * LW * 2 + 256 <= ws_size);
  short* wAll = nullptr;
  short *wqkvT = nullptr, *woT = nullptr, *w1T = nullptr, *w2T = nullptr;
  if (big) {
    wAll = (short*)alloc((size_t)12 * LW * 2);
  } else {
    wqkvT = (short*)alloc((size_t)2304 * 768 * 2);
    woT = (short*)alloc((size_t)768 * 768 * 2);
    w1T = (short*)alloc((size_t)3072 * 768 * 2);
    w2T = (short*)alloc((size_t)768 * 3072 * 2);
    if (off > ws_size) return;
  }

  const dim3 tb(32, 8);
  transpose_convert<<<dim3(1572, 24, 1), tb, 0, stream>>>(lm_w, lmT, 768, 50257, 0, 0);
  if (big) {
    transpose_convert<<<dim3(24, 24, 12), tb, 0, stream>>>(wq, wAll + 0, 768, 768, dd, LW);
    transpose_convert<<<dim3(24, 24, 12), tb, 0, stream>>>(wk, wAll + 589824, 768, 768, dd, LW);
    transpose_convert<<<dim3(24, 24, 12), tb, 0, stream>>>(wv, wAll + 1179648, 768, 768, dd, LW);
    transpose_convert<<<dim3(24, 24, 12), tb, 0, stream>>>(wo, wAll + 1769472, 768, 768, dd, LW);
    transpose_convert<<<dim3(96, 24, 12), tb, 0, stream>>>(w1, wAll + 2359296, 768, 3072,
                                                           (size_t)768 * 3072, LW);
    transpose_convert<<<dim3(24, 96, 12), tb, 0, stream>>>(w2, wAll + 4718592, 3072, 768,
                                                           (size_t)3072 * 768, LW);
  }
  embed_kernel<<<4096, 256, 0, stream>>>(idx, wte, wpe, x);

  for (int l = 0; l < 12; ++l) {
    const short *pQKV, *pWO, *pW1, *pW2;
    if (big) {
      short* wl = wAll + (size_t)l * LW;
      pQKV = wl;
      pWO = wl + 1769472;
      pW1 = wl + 2359296;
      pW2 = wl + 4718592;
    } else {
      transpose_convert<<<dim3(24, 24, 1), tb, 0, stream>>>(wq + l * dd, wqkvT, 768, 768, 0, 0);
      transpose_convert<<<dim3(24, 24, 1), tb, 0, stream>>>(wk + l * dd, wqkvT + dd, 768, 768, 0, 0);
      transpose_convert<<<dim3(24, 24, 1), tb, 0, stream>>>(wv + l * dd, wqkvT + 2 * dd, 768, 768, 0, 0);
      transpose_convert<<<dim3(24, 24, 1), tb, 0, stream>>>(wo + l * dd, woT, 768, 768, 0, 0);
      transpose_convert<<<dim3(96, 24, 1), tb, 0, stream>>>(w1 + (size_t)l * 768 * 3072, w1T, 768, 3072, 0, 0);
      transpose_convert<<<dim3(24, 96, 1), tb, 0, stream>>>(w2 + (size_t)l * 3072 * 768, w2T, 3072, 768, 0, 0);
      pQKV = wqkvT; pWO = woT; pW1 = w1T; pW2 = w2T;
    }

    ln_kernel<<<4096, 256, 0, stream>>>(x, ln1_g + l * 768, ln1_b + l * 768, h);
    gemm_kernel<128, 64, EPI_QKV><<<dim3(32, 36), 256, 0, stream>>>(
        h, pQKV, 768, bq + l * 768, bk + l * 768, bv + l * 768, nullptr, qb, kb, vtb);
    attn_kernel<<<dim3(48, 16), 256, 0, stream>>>(qb, kb, vtb, ob);
    gemm_kernel<64, 64, EPI_RESID><<<dim3(64, 12), 256, 0, stream>>>(
        ob, pWO, 768, bo + l * 768, nullptr, nullptr, x, nullptr, nullptr, nullptr);
    ln_kernel<<<4096, 256, 0, stream>>>(x, ln2_g + l * 768, ln2_b + l * 768, h);
    gemm_kernel<128, 64, EPI_GELU><<<dim3(32, 48), 256, 0, stream>>>(
        h, pW1, 768, b1 + l * 3072, nullptr, nullptr, nullptr, ff, nullptr, nullptr);
    gemm_kernel<64, 64, EPI_RESID><<<dim3(64, 12), 256, 0, stream>>>(
        ff, pW2, 3072, b2 + l * 768, nullptr, nullptr, x, nullptr, nullptr, nullptr);
  }

  ln_kernel<<<4096, 256, 0, stream>>>(x, lnf_g, lnf_b, h);
  gemm_kernel<128, 128, EPI_LM><<<dim3(32, 393), 256, 0, stream>>>(
      h, lmT, 768, nullptr, nullptr, nullptr, out, nullptr, nullptr, nullptr);
}

// Round 7
// 3059.219 us; speedup vs baseline: 1.3770x; 1.0692x over previous
//
#include <hip/hip_runtime.h>
#include <hip/hip_bf16.h>

typedef __attribute__((ext_vector_type(8))) short short8;
typedef __attribute__((ext_vector_type(4))) float floatx4;

#define GLD16(g, l) __builtin_amdgcn_global_load_lds( \
    (__attribute__((address_space(1))) void*)(g),      \
    (__attribute__((address_space(3))) void*)(l), 16, 0, 0)

#define MFMA_BF16(a, b, c) __builtin_amdgcn_mfma_f32_16x16x32_bf16((a), (b), (c), 0, 0, 0)

__device__ __forceinline__ short f2bf(float f) {
  union { __hip_bfloat16 h; short s; } u;
  u.h = __float2bfloat16(f);
  return u.s;
}

// ---------------------------------------------------------------------------
// transpose + fp32->bf16 convert:  in fp32 [K][N] -> out bf16 [Npad][K]
// ---------------------------------------------------------------------------
__global__ __launch_bounds__(256)
void transpose_convert(const float* __restrict__ in, short* __restrict__ out,
                       const int K, const int N, const size_t inStride,
                       const size_t outStride) {
  in += blockIdx.z * inStride;
  out += blockIdx.z * outStride;
  __shared__ float tile[32][33];
  const int n0 = blockIdx.x * 32;
  const int k0 = blockIdx.y * 32;
  const int tx = threadIdx.x;
  const int ty = threadIdx.y;
#pragma unroll
  for (int i = 0; i < 4; ++i) {
    const int kk = ty + i * 8;
    const int nn = n0 + tx;
    tile[kk][tx] = (nn < N) ? in[(size_t)(k0 + kk) * N + nn] : 0.f;
  }
  __syncthreads();
#pragma unroll
  for (int i = 0; i < 4; ++i) {
    const int nn = ty + i * 8;
    out[(size_t)(n0 + nn) * K + k0 + tx] = f2bf(tile[tx][nn]);
  }
}

// ---------------------------------------------------------------------------
__global__ __launch_bounds__(256)
void embed_kernel(const int* __restrict__ idx, const float* __restrict__ wte,
                  const float* __restrict__ wpe, float* __restrict__ x) {
  const int row = blockIdx.x;
  const int tok = idx[row];
  const int s = row & 1023;
  const float* wt = wte + (size_t)tok * 768;
  const float* wp = wpe + (size_t)s * 768;
  float* xr = x + (size_t)row * 768;
  for (int c = threadIdx.x; c < 768; c += 256) xr[c] = wt[c] + wp[c];
}

// ---------------------------------------------------------------------------
__global__ __launch_bounds__(256)
void ln_kernel(const float* __restrict__ x, const float* __restrict__ g,
               const float* __restrict__ b, short* __restrict__ out) {
  const int row = blockIdx.x;
  const int t = threadIdx.x;
  const int wv = t >> 6, lane = t & 63;
  const float* xr = x + (size_t)row * 768;
  const float v0 = xr[t], v1 = xr[t + 256], v2 = xr[t + 512];
  __shared__ float red[4];
  float s = v0 + v1 + v2;
#pragma unroll
  for (int m = 1; m < 64; m <<= 1) s += __shfl_xor(s, m);
  if (lane == 0) red[wv] = s;
  __syncthreads();
  const float mean = (red[0] + red[1] + red[2] + red[3]) * (1.0f / 768.0f);
  __syncthreads();
  const float d0 = v0 - mean, d1 = v1 - mean, d2 = v2 - mean;
  float q = d0 * d0 + d1 * d1 + d2 * d2;
#pragma unroll
  for (int m = 1; m < 64; m <<= 1) q += __shfl_xor(q, m);
  if (lane == 0) red[wv] = q;
  __syncthreads();
  const float var = (red[0] + red[1] + red[2] + red[3]) * (1.0f / 768.0f);
  const float inv = rsqrtf(var + 1e-5f);
  short* orow = out + (size_t)row * 768;
  orow[t] = f2bf(d0 * inv * g[t] + b[t]);
  orow[t + 256] = f2bf(d1 * inv * g[t + 256] + b[t + 256]);
  orow[t + 512] = f2bf(d2 * inv * g[t + 512] + b[t + 512]);
}

// ---------------------------------------------------------------------------
// GEMM: BMxBN tile, BK=64, unit-XOR swizzle (proven r6: bank conflicts -> 0).
// DBUF=1: double-buffered (layer GEMMs, 48/32KB LDS, 3-5 blocks/CU).
// DBUF=0: single-buffered (LM: 32KB LDS -> 3 blocks/CU; cross-block TLP
//         hides the stage, m97-style — dbuf at 64KB cost occupancy, r6).
// ---------------------------------------------------------------------------
enum { EPI_QKV = 0, EPI_RESID = 1, EPI_GELU = 2, EPI_LM = 3 };

template <int BM, int BN>
__device__ __forceinline__ void stage_tiles(const short* __restrict__ Ab,
                                            const short* __restrict__ Bb,
                                            const int K, const int kb,
                                            short* pa, short* pb,
                                            const int tid, const int wv) {
#pragma unroll
  for (int i = 0; i < BM / 32; ++i) {
    const int p = i * 256 + tid;
    const int rr = p >> 3, up = p & 7;
    GLD16(Ab + (size_t)rr * K + kb + ((up ^ (rr & 7)) << 3),
          pa + (i * 256 + wv * 64) * 8);
  }
#pragma unroll
  for (int i = 0; i < BN / 32; ++i) {
    const int p = i * 256 + tid;
    const int rr = p >> 3, up = p & 7;
    GLD16(Bb + (size_t)rr * K + kb + ((up ^ (rr & 7)) << 3),
          pb + (i * 256 + wv * 64) * 8);
  }
}

template <int BM, int BN, int DBUF, int EPI>
__global__ __launch_bounds__(256)
void gemm_kernel(const short* __restrict__ A, const short* __restrict__ Bt,
                 const int K,
                 const float* __restrict__ bias0, const float* __restrict__ bias1,
                 const float* __restrict__ bias2, float* __restrict__ fout,
                 short* __restrict__ bout0, short* __restrict__ bout1,
                 short* __restrict__ bout2) {
  constexpr int MF = BM / 32;
  constexpr int NF = BN / 32;
  __shared__ short sA[DBUF + 1][BM * 64];
  __shared__ short sB[DBUF + 1][BN * 64];
  const int tid = threadIdx.x;
  const int wv = tid >> 6;
  const int lane = tid & 63;
  const int lrow = lane & 15;
  const int lk8 = lane >> 4;
  const int m0 = blockIdx.x * BM;
  const int n0 = blockIdx.y * BN;
  const int wm = (wv >> 1) * (BM / 2);
  const int wn = (wv & 1) * (BN / 2);

  floatx4 acc[MF][NF];
#pragma unroll
  for (int m = 0; m < MF; ++m)
#pragma unroll
    for (int n = 0; n < NF; ++n) acc[m][n] = {0.f, 0.f, 0.f, 0.f};

  const short* Ab = A + (size_t)m0 * K;
  const short* Bb = Bt + (size_t)n0 * K;

  auto compute = [&](const short* pa, const short* pb) {
    short8 af[MF][2], bv[NF][2];
#pragma unroll
    for (int m = 0; m < MF; ++m)
#pragma unroll
      for (int ks = 0; ks < 2; ++ks)
        af[m][ks] = *(const short8*)(pa + (wm + m * 16 + lrow) * 64 +
                                     (((ks * 4 + lk8) ^ (lrow & 7)) << 3));
#pragma unroll
    for (int n = 0; n < NF; ++n)
#pragma unroll
      for (int ks = 0; ks < 2; ++ks)
        bv[n][ks] = *(const short8*)(pb + (wn + n * 16 + lrow) * 64 +
                                     (((ks * 4 + lk8) ^ (lrow & 7)) << 3));
#pragma unroll
    for (int m = 0; m < MF; ++m)
#pragma unroll
      for (int n = 0; n < NF; ++n) {
        acc[m][n] = MFMA_BF16(af[m][0], bv[n][0], acc[m][n]);
        acc[m][n] = MFMA_BF16(af[m][1], bv[n][1], acc[m][n]);
      }
  };

  const int nk = K >> 6;
  if (DBUF) {
    stage_tiles<BM, BN>(Ab, Bb, K, 0, sA[0], sB[0], tid, wv);
    __syncthreads();
    int cur = 0;
    for (int kt = 0; kt < nk; ++kt) {
      if (kt + 1 < nk)
        stage_tiles<BM, BN>(Ab, Bb, K, (kt + 1) << 6, sA[cur ^ 1],
                            sB[cur ^ 1], tid, wv);
      compute(sA[cur], sB[cur]);
      __syncthreads();
      cur ^= 1;
    }
  } else {
    for (int kt = 0; kt < nk; ++kt) {
      stage_tiles<BM, BN>(Ab, Bb, K, kt << 6, sA[0], sB[0], tid, wv);
      __syncthreads();
      compute(sA[0], sB[0]);
      __syncthreads();
    }
  }

#pragma unroll
  for (int m = 0; m < MF; ++m) {
#pragma unroll
    for (int n = 0; n < NF; ++n) {
#pragma unroll
      for (int r = 0; r < 4; ++r) {
        const float v = acc[m][n][r];
        const int gm = m0 + wm + m * 16 + lk8 * 4 + r;
        const int gn = n0 + wn + n * 16 + lrow;
        if (EPI == EPI_QKV) {
          const int sec = (gn >= 1536) ? 2 : (gn >= 768 ? 1 : 0);
          const int nn = gn - sec * 768;
          const int hh = nn >> 6, dh = nn & 63;
          const int bb = gm >> 10, srow = gm & 1023;
          if (sec == 0) {
            bout0[(((size_t)(bb * 12 + hh) * 1024 + srow) << 6) + dh] =
                f2bf((v + bias0[nn]) * 0.125f);
          } else if (sec == 1) {
            bout1[(((size_t)(bb * 12 + hh) * 1024 + srow) << 6) + dh] =
                f2bf(v + bias1[nn]);
          } else {
            bout2[(((size_t)(bb * 12 + hh) * 64 + dh) << 10) + srow] =
                f2bf(v + bias2[nn]);
          }
        } else if (EPI == EPI_RESID) {
          float* xp = fout + (size_t)gm * 768 + gn;
          *xp = *xp + v + bias0[gn];
        } else if (EPI == EPI_GELU) {
          const float tt = v + bias0[gn];
          const float gl = 0.5f * tt * (1.f + erff(tt * 0.70710678118654752f));
          bout0[(size_t)gm * 3072 + gn] = f2bf(gl);
        } else {  // EPI_LM
          if (gn < 50257) fout[(size_t)gm * 50257 + gn] = v;
        }
      }
    }
  }
}

// ---------------------------------------------------------------------------
// flash attention (causal), LDS-staged K/V, heavy q-blocks first.
// lsum kept as per-lane partials; reduced once in epilogue (sf is
// row-group-uniform so partials rescale consistently).
// q,k [48][1024][64] bf16 (q pre-scaled 1/8), vt [48][64][1024] bf16
// -> o [4096][768] bf16. grid (48,16), block 256.
// ---------------------------------------------------------------------------
__global__ __launch_bounds__(256)
void attn_kernel(const short* __restrict__ q, const short* __restrict__ k,
                 const short* __restrict__ vt, short* __restrict__ o) {
  __shared__ short sK[64 * 64];
  __shared__ short sV[64 * 64];
  __shared__ short sP[4][16 * 64];
  const int bh = blockIdx.x;
  const int qi = 15 - blockIdx.y;
  const int tid = threadIdx.x;
  const int wv = tid >> 6, lane = tid & 63;
  const int lrow = lane & 15, lk8 = lane >> 4;
  const int q0 = qi * 64;

  const short* qg = q + ((size_t)(bh * 1024 + q0 + wv * 16 + lrow)) * 64 + lk8 * 8;
  const short8 qf0 = *(const short8*)qg;
  const short8 qf1 = *(const short8*)(qg + 32);

  float m_run[4], lsum[4];
  floatx4 accO[4];
#pragma unroll
  for (int r = 0; r < 4; ++r) { m_run[r] = -1e30f; lsum[r] = 0.f; }
#pragma unroll
  for (int n = 0; n < 4; ++n) accO[n] = {0.f, 0.f, 0.f, 0.f};

  for (int t = 0; t <= qi; ++t) {
    const int k0 = t * 64;
#pragma unroll
    for (int i = 0; i < 2; ++i) {
      const int e = (i * 256 + tid) * 8;
      const int r = e >> 6, cc = e & 63;
      const int su = ((cc >> 3) ^ (r & 7)) << 3;
      *(short8*)(sK + r * 64 + su) =
          *(const short8*)(k + ((size_t)(bh * 1024 + k0 + r)) * 64 + cc);
      *(short8*)(sV + r * 64 + su) =
          *(const short8*)(vt + ((size_t)(bh * 64 + r)) * 1024 + k0 + cc);
    }
    __syncthreads();

    floatx4 accS[4];
#pragma unroll
    for (int n = 0; n < 4; ++n) accS[n] = {0.f, 0.f, 0.f, 0.f};
#pragma unroll
    for (int ks = 0; ks < 2; ++ks) {
      const short8 qf = ks ? qf1 : qf0;
      const int u = lk8 + ks * 4;
#pragma unroll
      for (int n = 0; n < 4; ++n) {
        const int key = n * 16 + lrow;
        const short8 kf = *(const short8*)(sK + key * 64 + ((u ^ (key & 7)) << 3));
        accS[n] = MFMA_BF16(qf, kf, accS[n]);
      }
    }

#pragma unroll
    for (int r = 0; r < 4; ++r) {
      const int qrow = q0 + wv * 16 + lk8 * 4 + r;
      float sv[4];
      float mx = -1e30f;
#pragma unroll
      for (int n = 0; n < 4; ++n) {
        float s = accS[n][r];
        const int key = k0 + n * 16 + lrow;
        s = (key > qrow) ? -1e30f : s;
        sv[n] = s;
        mx = fmaxf(mx, s);
      }
#pragma unroll
      for (int m = 1; m < 16; m <<= 1) mx = fmaxf(mx, __shfl_xor(mx, m));
      const float mnew = fmaxf(m_run[r], mx);
      const float sf = __expf(m_run[r] - mnew);
      m_run[r] = mnew;
      float rs = 0.f;
      const int prow = lk8 * 4 + r;
#pragma unroll
      for (int n = 0; n < 4; ++n) {
        const float pv = __expf(sv[n] - mnew);
        rs += pv;
        const int col = n * 16 + lrow;
        sP[wv][prow * 64 + (((col >> 3) ^ (prow & 7)) << 3) + (col & 7)] = f2bf(pv);
      }
      lsum[r] = lsum[r] * sf + rs;  // per-lane partial; reduced in epilogue
#pragma unroll
      for (int n = 0; n < 4; ++n) accO[n][r] *= sf;
    }

#pragma unroll
    for (int ks = 0; ks < 2; ++ks) {
      const int u = lk8 + ks * 4;
      const short8 pf =
          *(const short8*)(&sP[wv][lrow * 64 + ((u ^ (lrow & 7)) << 3)]);
#pragma unroll
      for (int n = 0; n < 4; ++n) {
        const int dh = n * 16 + lrow;
        const short8 vf = *(const short8*)(sV + dh * 64 + ((u ^ (dh & 7)) << 3));
        accO[n] = MFMA_BF16(pf, vf, accO[n]);
      }
    }
    __syncthreads();
  }

  float inv[4];
#pragma unroll
  for (int r = 0; r < 4; ++r) {
    float ls = lsum[r];
#pragma unroll
    for (int m = 1; m < 16; m <<= 1) ls += __shfl_xor(ls, m);
    inv[r] = 1.f / ls;
  }

  const int bb = bh / 12, hh = bh % 12;
#pragma unroll
  for (int n = 0; n < 4; ++n)
#pragma unroll
    for (int r = 0; r < 4; ++r) {
      const int row = q0 + wv * 16 + lk8 * 4 + r;
      const float ov = accO[n][r] * inv[r];
      o[((size_t)(bb * 1024 + row)) * 768 + hh * 64 + n * 16 + lrow] = f2bf(ov);
    }
}

// ---------------------------------------------------------------------------
extern "C" void kernel_launch(void* const* d_in, const int* in_sizes, int n_in,
                              void* d_out, int out_size, void* d_ws, size_t ws_size,
                              hipStream_t stream) {
  const int* idx = (const int*)d_in[0];
  const float* wte = (const float*)d_in[1];
  const float* wpe = (const float*)d_in[2];
  const float* ln1_g = (const float*)d_in[3];
  const float* ln1_b = (const float*)d_in[4];
  const float* wq = (const float*)d_in[5];
  const float* bq = (const float*)d_in[6];
  const float* wk = (const float*)d_in[7];
  const float* bk = (const float*)d_in[8];
  const float* wv = (const float*)d_in[9];
  const float* bv = (const float*)d_in[10];
  const float* wo = (const float*)d_in[11];
  const float* bo = (const float*)d_in[12];
  const float* ln2_g = (const float*)d_in[13];
  const float* ln2_b = (const float*)d_in[14];
  const float* w1 = (const float*)d_in[15];
  const float* b1 = (const float*)d_in[16];
  const float* w2 = (const float*)d_in[17];
  const float* b2 = (const float*)d_in[18];
  const float* lnf_g = (const float*)d_in[19];
  const float* lnf_b = (const float*)d_in[20];
  const float* lm_w = (const float*)d_in[21];
  float* out = (float*)d_out;

  char* base = (char*)d_ws;
  size_t off = 0;
  auto alloc = [&](size_t bytes) {
    char* r = base + off;
    off = (off + bytes + 255) & ~(size_t)255;
    return r;
  };
  short* lmT = (short*)alloc((size_t)50304 * 768 * 2);
  float* x = (float*)alloc((size_t)4096 * 768 * 4);
  short* h = (short*)alloc((size_t)4096 * 768 * 2);
  short* qb = (short*)alloc((size_t)4096 * 768 * 2);
  short* kb = (short*)alloc((size_t)4096 * 768 * 2);
  short* vtb = (short*)alloc((size_t)4096 * 768 * 2);
  short* ob = (short*)alloc((size_t)4096 * 768 * 2);
  short* ff = (short*)alloc((size_t)4096 * 3072 * 2);

  const size_t LW = 7077888;  // elements per layer weight block
  const size_t dd = (size_t)768 * 768;
  const bool big = (off + (size_t)12 * LW * 2 + 256 <= ws_size);
  short* wAll = nullptr;
  short *wqkvT = nullptr, *woT = nullptr, *w1T = nullptr, *w2T = nullptr;
  if (big) {
    wAll = (short*)alloc((size_t)12 * LW * 2);
  } else {
    wqkvT = (short*)alloc((size_t)2304 * 768 * 2);
    woT = (short*)alloc((size_t)768 * 768 * 2);
    w1T = (short*)alloc((size_t)3072 * 768 * 2);
    w2T = (short*)alloc((size_t)768 * 3072 * 2);
    if (off > ws_size) return;
  }

  const dim3 tb(32, 8);
  transpose_convert<<<dim3(1572, 24, 1), tb, 0, stream>>>(lm_w, lmT, 768, 50257, 0, 0);
  if (big) {
    transpose_convert<<<dim3(24, 24, 12), tb, 0, stream>>>(wq, wAll + 0, 768, 768, dd, LW);
    transpose_convert<<<dim3(24, 24, 12), tb, 0, stream>>>(wk, wAll + 589824, 768, 768, dd, LW);
    transpose_convert<<<dim3(24, 24, 12), tb, 0, stream>>>(wv, wAll + 1179648, 768, 768, dd, LW);
    transpose_convert<<<dim3(24, 24, 12), tb, 0, stream>>>(wo, wAll + 1769472, 768, 768, dd, LW);
    transpose_convert<<<dim3(96, 24, 12), tb, 0, stream>>>(w1, wAll + 2359296, 768, 3072,
                                                           (size_t)768 * 3072, LW);
    transpose_convert<<<dim3(24, 96, 12), tb, 0, stream>>>(w2, wAll + 4718592, 3072, 768,
                                                           (size_t)3072 * 768, LW);
  }
  embed_kernel<<<4096, 256, 0, stream>>>(idx, wte, wpe, x);

  for (int l = 0; l < 12; ++l) {
    const short *pQKV, *pWO, *pW1, *pW2;
    if (big) {
      short* wl = wAll + (size_t)l * LW;
      pQKV = wl;
      pWO = wl + 1769472;
      pW1 = wl + 2359296;
      pW2 = wl + 4718592;
    } else {
      transpose_convert<<<dim3(24, 24, 1), tb, 0, stream>>>(wq + l * dd, wqkvT, 768, 768, 0, 0);
      transpose_convert<<<dim3(24, 24, 1), tb, 0, stream>>>(wk + l * dd, wqkvT + dd, 768, 768, 0, 0);
      transpose_convert<<<dim3(24, 24, 1), tb, 0, stream>>>(wv + l * dd, wqkvT + 2 * dd, 768, 768, 0, 0);
      transpose_convert<<<dim3(24, 24, 1), tb, 0, stream>>>(wo + l * dd, woT, 768, 768, 0, 0);
      transpose_convert<<<dim3(96, 24, 1), tb, 0, stream>>>(w1 + (size_t)l * 768 * 3072, w1T, 768, 3072, 0, 0);
      transpose_convert<<<dim3(24, 96, 1), tb, 0, stream>>>(w2 + (size_t)l * 3072 * 768, w2T, 3072, 768, 0, 0);
      pQKV = wqkvT; pWO = woT; pW1 = w1T; pW2 = w2T;
    }

    ln_kernel<<<4096, 256, 0, stream>>>(x, ln1_g + l * 768, ln1_b + l * 768, h);
    gemm_kernel<128, 64, 1, EPI_QKV><<<dim3(32, 36), 256, 0, stream>>>(
        h, pQKV, 768, bq + l * 768, bk + l * 768, bv + l * 768, nullptr, qb, kb, vtb);
    attn_kernel<<<dim3(48, 16), 256, 0, stream>>>(qb, kb, vtb, ob);
    gemm_kernel<64, 64, 1, EPI_RESID><<<dim3(64, 12), 256, 0, stream>>>(
        ob, pWO, 768, bo + l * 768, nullptr, nullptr, x, nullptr, nullptr, nullptr);
    ln_kernel<<<4096, 256, 0, stream>>>(x, ln2_g + l * 768, ln2_b + l * 768, h);
    gemm_kernel<128, 64, 1, EPI_GELU><<<dim3(32, 48), 256, 0, stream>>>(
        h, pW1, 768, b1 + l * 3072, nullptr, nullptr, nullptr, ff, nullptr, nullptr);
    gemm_kernel<64, 64, 1, EPI_RESID><<<dim3(64, 12), 256, 0, stream>>>(
        ff, pW2, 3072, b2 + l * 768, nullptr, nullptr, x, nullptr, nullptr, nullptr);
  }

  ln_kernel<<<4096, 256, 0, stream>>>(x, lnf_g, lnf_b, h);
  gemm_kernel<128, 128, 0, EPI_LM><<<dim3(32, 393), 256, 0, stream>>>(
      h, lmT, 768, nullptr, nullptr, nullptr, out, nullptr, nullptr, nullptr);
}

// Round 9
// 2885.649 us; speedup vs baseline: 1.4598x; 1.0601x over previous
//
#include <hip/hip_runtime.h>
#include <hip/hip_bf16.h>

typedef __attribute__((ext_vector_type(8))) short short8;
typedef __attribute__((ext_vector_type(4))) float floatx4;

#define GLD16(g, l) __builtin_amdgcn_global_load_lds( \
    (__attribute__((address_space(1))) void*)(g),      \
    (__attribute__((address_space(3))) void*)(l), 16, 0, 0)

#define MFMA_BF16(a, b, c) __builtin_amdgcn_mfma_f32_16x16x32_bf16((a), (b), (c), 0, 0, 0)

__device__ __forceinline__ short f2bf(float f) {
  union { __hip_bfloat16 h; short s; } u;
  u.h = __float2bfloat16(f);
  return u.s;
}

// ---------------------------------------------------------------------------
// transpose + fp32->bf16 convert:  in fp32 [K][N] -> out bf16 [Npad][K]
// ---------------------------------------------------------------------------
__global__ __launch_bounds__(256)
void transpose_convert(const float* __restrict__ in, short* __restrict__ out,
                       const int K, const int N, const size_t inStride,
                       const size_t outStride) {
  in += blockIdx.z * inStride;
  out += blockIdx.z * outStride;
  __shared__ float tile[32][33];
  const int n0 = blockIdx.x * 32;
  const int k0 = blockIdx.y * 32;
  const int tx = threadIdx.x;
  const int ty = threadIdx.y;
#pragma unroll
  for (int i = 0; i < 4; ++i) {
    const int kk = ty + i * 8;
    const int nn = n0 + tx;
    tile[kk][tx] = (nn < N) ? in[(size_t)(k0 + kk) * N + nn] : 0.f;
  }
  __syncthreads();
#pragma unroll
  for (int i = 0; i < 4; ++i) {
    const int nn = ty + i * 8;
    out[(size_t)(n0 + nn) * K + k0 + tx] = f2bf(tile[tx][nn]);
  }
}

// ---------------------------------------------------------------------------
__global__ __launch_bounds__(256)
void embed_kernel(const int* __restrict__ idx, const float* __restrict__ wte,
                  const float* __restrict__ wpe, float* __restrict__ x) {
  const int row = blockIdx.x;
  const int tok = idx[row];
  const int s = row & 1023;
  const float* wt = wte + (size_t)tok * 768;
  const float* wp = wpe + (size_t)s * 768;
  float* xr = x + (size_t)row * 768;
  for (int c = threadIdx.x; c < 768; c += 256) xr[c] = wt[c] + wp[c];
}

// ---------------------------------------------------------------------------
__global__ __launch_bounds__(256)
void ln_kernel(const float* __restrict__ x, const float* __restrict__ g,
               const float* __restrict__ b, short* __restrict__ out) {
  const int row = blockIdx.x;
  const int t = threadIdx.x;
  const int wv = t >> 6, lane = t & 63;
  const float* xr = x + (size_t)row * 768;
  const float v0 = xr[t], v1 = xr[t + 256], v2 = xr[t + 512];
  __shared__ float red[4];
  float s = v0 + v1 + v2;
#pragma unroll
  for (int m = 1; m < 64; m <<= 1) s += __shfl_xor(s, m);
  if (lane == 0) red[wv] = s;
  __syncthreads();
  const float mean = (red[0] + red[1] + red[2] + red[3]) * (1.0f / 768.0f);
  __syncthreads();
  const float d0 = v0 - mean, d1 = v1 - mean, d2 = v2 - mean;
  float q = d0 * d0 + d1 * d1 + d2 * d2;
#pragma unroll
  for (int m = 1; m < 64; m <<= 1) q += __shfl_xor(q, m);
  if (lane == 0) red[wv] = q;
  __syncthreads();
  const float var = (red[0] + red[1] + red[2] + red[3]) * (1.0f / 768.0f);
  const float inv = rsqrtf(var + 1e-5f);
  short* orow = out + (size_t)row * 768;
  orow[t] = f2bf(d0 * inv * g[t] + b[t]);
  orow[t + 256] = f2bf(d1 * inv * g[t + 256] + b[t + 256]);
  orow[t + 512] = f2bf(d2 * inv * g[t + 512] + b[t + 512]);
}

// ---------------------------------------------------------------------------
// Layer GEMM: BMx64 tile, BK=64, unit-XOR swizzle (r6: conflicts -> 0),
// double-buffered, 256 threads = 4 waves.
// ---------------------------------------------------------------------------
enum { EPI_QKV = 0, EPI_RESID = 1, EPI_GELU = 2 };

template <int BM, int BN>
__device__ __forceinline__ void stage_tiles(const short* __restrict__ Ab,
                                            const short* __restrict__ Bb,
                                            const int K, const int kb,
                                            short* pa, short* pb,
                                            const int tid, const int wv) {
#pragma unroll
  for (int i = 0; i < BM / 32; ++i) {
    const int p = i * 256 + tid;
    const int rr = p >> 3, up = p & 7;
    GLD16(Ab + (size_t)rr * K + kb + ((up ^ (rr & 7)) << 3),
          pa + (i * 256 + wv * 64) * 8);
  }
#pragma unroll
  for (int i = 0; i < BN / 32; ++i) {
    const int p = i * 256 + tid;
    const int rr = p >> 3, up = p & 7;
    GLD16(Bb + (size_t)rr * K + kb + ((up ^ (rr & 7)) << 3),
          pb + (i * 256 + wv * 64) * 8);
  }
}

template <int BM, int BN, int EPI>
__global__ __launch_bounds__(256)
void gemm_kernel(const short* __restrict__ A, const short* __restrict__ Bt,
                 const int K,
                 const float* __restrict__ bias0, const float* __restrict__ bias1,
                 const float* __restrict__ bias2, float* __restrict__ fout,
                 short* __restrict__ bout0, short* __restrict__ bout1,
                 short* __restrict__ bout2) {
  constexpr int MF = BM / 32;
  constexpr int NF = BN / 32;
  __shared__ short sA[2][BM * 64];
  __shared__ short sB[2][BN * 64];
  const int tid = threadIdx.x;
  const int wv = tid >> 6;
  const int lane = tid & 63;
  const int lrow = lane & 15;
  const int lk8 = lane >> 4;
  const int m0 = blockIdx.x * BM;
  const int n0 = blockIdx.y * BN;
  const int wm = (wv >> 1) * (BM / 2);
  const int wn = (wv & 1) * (BN / 2);

  floatx4 acc[MF][NF];
#pragma unroll
  for (int m = 0; m < MF; ++m)
#pragma unroll
    for (int n = 0; n < NF; ++n) acc[m][n] = {0.f, 0.f, 0.f, 0.f};

  const short* Ab = A + (size_t)m0 * K;
  const short* Bb = Bt + (size_t)n0 * K;

  const int nk = K >> 6;
  stage_tiles<BM, BN>(Ab, Bb, K, 0, sA[0], sB[0], tid, wv);
  __syncthreads();

  int cur = 0;
  for (int kt = 0; kt < nk; ++kt) {
    if (kt + 1 < nk)
      stage_tiles<BM, BN>(Ab, Bb, K, (kt + 1) << 6, sA[cur ^ 1], sB[cur ^ 1],
                          tid, wv);
    const short* pa = sA[cur];
    const short* pb = sB[cur];
    short8 af[MF][2], bv[NF][2];
#pragma unroll
    for (int m = 0; m < MF; ++m)
#pragma unroll
      for (int ks = 0; ks < 2; ++ks)
        af[m][ks] = *(const short8*)(pa + (wm + m * 16 + lrow) * 64 +
                                     (((ks * 4 + lk8) ^ (lrow & 7)) << 3));
#pragma unroll
    for (int n = 0; n < NF; ++n)
#pragma unroll
      for (int ks = 0; ks < 2; ++ks)
        bv[n][ks] = *(const short8*)(pb + (wn + n * 16 + lrow) * 64 +
                                     (((ks * 4 + lk8) ^ (lrow & 7)) << 3));
#pragma unroll
    for (int m = 0; m < MF; ++m)
#pragma unroll
      for (int n = 0; n < NF; ++n) {
        acc[m][n] = MFMA_BF16(af[m][0], bv[n][0], acc[m][n]);
        acc[m][n] = MFMA_BF16(af[m][1], bv[n][1], acc[m][n]);
      }
    __syncthreads();
    cur ^= 1;
  }

#pragma unroll
  for (int m = 0; m < MF; ++m) {
#pragma unroll
    for (int n = 0; n < NF; ++n) {
#pragma unroll
      for (int r = 0; r < 4; ++r) {
        const float v = acc[m][n][r];
        const int gm = m0 + wm + m * 16 + lk8 * 4 + r;
        const int gn = n0 + wn + n * 16 + lrow;
        if (EPI == EPI_QKV) {
          const int sec = (gn >= 1536) ? 2 : (gn >= 768 ? 1 : 0);
          const int nn = gn - sec * 768;
          const int hh = nn >> 6, dh = nn & 63;
          const int bb = gm >> 10, srow = gm & 1023;
          if (sec == 0) {
            // q pre-scaled by 0.125 * log2(e) so attention can use exp2
            bout0[(((size_t)(bb * 12 + hh) * 1024 + srow) << 6) + dh] =
                f2bf((v + bias0[nn]) * 0.18033688f);
          } else if (sec == 1) {
            bout1[(((size_t)(bb * 12 + hh) * 1024 + srow) << 6) + dh] =
                f2bf(v + bias1[nn]);
          } else {
            bout2[(((size_t)(bb * 12 + hh) * 64 + dh) << 10) + srow] =
                f2bf(v + bias2[nn]);
          }
        } else if (EPI == EPI_RESID) {
          float* xp = fout + (size_t)gm * 768 + gn;
          *xp = *xp + v + bias0[gn];
        } else {  // EPI_GELU
          const float tt = v + bias0[gn];
          const float gl = 0.5f * tt * (1.f + erff(tt * 0.70710678118654752f));
          bout0[(size_t)gm * 3072 + gn] = f2bf(gl);
        }
      }
    }
  }
}

// ---------------------------------------------------------------------------
// LM-head GEMM: 256x128, BK=64, 512 threads = 8 waves (4Mx2N of 64x64),
// single-buffered swizzled LDS (48KB -> 2 blocks/CU with 128-reg cap),
// hoisted incrementing stage pointers (r7 VALU bloat fix).
// ---------------------------------------------------------------------------
__global__ __launch_bounds__(512, 4)
void gemm_lm_kernel(const short* __restrict__ A, const short* __restrict__ Bt,
                    float* __restrict__ fout) {
  __shared__ short sA[256 * 64];  // 32 KB
  __shared__ short sB[128 * 64];  // 16 KB
  const int K = 768;
  const int tid = threadIdx.x;
  const int wv = tid >> 6;
  const int lane = tid & 63;
  const int lrow = lane & 15;
  const int lk8 = lane >> 4;
  const int m0 = blockIdx.x * 256;
  const int n0 = blockIdx.y * 128;
  const int wm = (wv >> 1) * 64;
  const int wn = (wv & 1) * 64;

  floatx4 acc[4][4];
#pragma unroll
  for (int m = 0; m < 4; ++m)
#pragma unroll
    for (int n = 0; n < 4; ++n) acc[m][n] = {0.f, 0.f, 0.f, 0.f};

  const short* Ab = A + (size_t)m0 * K;
  const short* Bb = Bt + (size_t)n0 * K;

  const short* pA[4];
  const short* pB[2];
#pragma unroll
  for (int i = 0; i < 4; ++i) {
    const int p = i * 512 + tid;
    const int rr = p >> 3, up = p & 7;
    pA[i] = Ab + (size_t)rr * K + ((up ^ (rr & 7)) << 3);
  }
#pragma unroll
  for (int i = 0; i < 2; ++i) {
    const int p = i * 512 + tid;
    const int rr = p >> 3, up = p & 7;
    pB[i] = Bb + (size_t)rr * K + ((up ^ (rr & 7)) << 3);
  }

  const int arow = (wm + lrow) * 64;  // reused below via +m*16*64
  const int xr = (lrow & 7);

  for (int kt = 0; kt < 12; ++kt) {
#pragma unroll
    for (int i = 0; i < 4; ++i) {
      GLD16(pA[i], sA + (i * 512 + wv * 64) * 8);
      pA[i] += 64;
    }
#pragma unroll
    for (int i = 0; i < 2; ++i) {
      GLD16(pB[i], sB + (i * 512 + wv * 64) * 8);
      pB[i] += 64;
    }
    __syncthreads();

    short8 bvv[4][2];
#pragma unroll
    for (int n = 0; n < 4; ++n) {
      const int brow = (wn + n * 16 + lrow) * 64;
      bvv[n][0] = *(const short8*)(sB + brow + ((lk8 ^ xr) << 3));
      bvv[n][1] = *(const short8*)(sB + brow + (((4 + lk8) ^ xr) << 3));
    }
#pragma unroll
    for (int m = 0; m < 4; ++m) {
      const short8 a0 = *(const short8*)(sA + arow + m * 1024 + ((lk8 ^ xr) << 3));
      const short8 a1 =
          *(const short8*)(sA + arow + m * 1024 + (((4 + lk8) ^ xr) << 3));
#pragma unroll
      for (int n = 0; n < 4; ++n) {
        acc[m][n] = MFMA_BF16(a0, bvv[n][0], acc[m][n]);
        acc[m][n] = MFMA_BF16(a1, bvv[n][1], acc[m][n]);
      }
    }
    __syncthreads();
  }

#pragma unroll
  for (int m = 0; m < 4; ++m)
#pragma unroll
    for (int n = 0; n < 4; ++n)
#pragma unroll
      for (int r = 0; r < 4; ++r) {
        const int gm = m0 + wm + m * 16 + lk8 * 4 + r;
        const int gn = n0 + wn + n * 16 + lrow;
        if (gn < 50257) fout[(size_t)gm * 50257 + gn] = acc[m][n][r];
      }
}

// ---------------------------------------------------------------------------
// flash attention (causal), swapped QK^T (mfma(K,Q) -> S^T): softmax is
// fully per-lane (q=lrow, 16 keys/lane); K-row permutation rK(n,i) makes the
// PV A-fragment a pure in-register repack (no LDS round-trip, no shuffles).
// q,k [48][1024][64] bf16 (q pre-scaled 0.125*log2e -> exp2), vt [48][64][1024]
// -> o [4096][768] bf16. grid (48,16), block 256, heavy q-blocks first.
// ---------------------------------------------------------------------------
__global__ __launch_bounds__(256)
void attn_kernel(const short* __restrict__ q, const short* __restrict__ k,
                 const short* __restrict__ vt, short* __restrict__ o) {
  __shared__ short sK[64 * 64];
  __shared__ short sV[64 * 64];
  const int bh = blockIdx.x;
  const int qi = 15 - blockIdx.y;
  const int tid = threadIdx.x;
  const int wv = tid >> 6, lane = tid & 63;
  const int lrow = lane & 15, lk8 = lane >> 4;
  const int q0 = qi * 64;
  const int qrow = q0 + wv * 16 + lrow;  // this lane's softmax row

  const short* qg = q + ((size_t)(bh * 1024 + qrow)) * 64 + lk8 * 8;
  const short8 qf0 = *(const short8*)qg;
  const short8 qf1 = *(const short8*)(qg + 32);

  float m_run = -1e30f, lsum = 0.f;
  floatx4 accO[4];
#pragma unroll
  for (int n = 0; n < 4; ++n) accO[n] = {0.f, 0.f, 0.f, 0.f};

  for (int t = 0; t <= qi; ++t) {
    const int k0 = t * 64;
#pragma unroll
    for (int i = 0; i < 2; ++i) {
      const int e = (i * 256 + tid) * 8;
      const int r = e >> 6, cc = e & 63;
      const int su = ((cc >> 3) ^ (r & 7)) << 3;
      *(short8*)(sK + r * 64 + su) =
          *(const short8*)(k + ((size_t)(bh * 1024 + k0 + r)) * 64 + cc);
      *(short8*)(sV + r * 64 + su) =
          *(const short8*)(vt + ((size_t)(bh * 64 + r)) * 1024 + k0 + cc);
    }
    __syncthreads();

    floatx4 accS[4];
#pragma unroll
    for (int n = 0; n < 4; ++n) accS[n] = {0.f, 0.f, 0.f, 0.f};
    // K-row permutation: A-row i of chunk n <- K row rK = 32(n>>1)+8(i>>2)+4(n&1)+(i&3)
    const int rKb = ((lrow >> 2) << 3) + (lrow & 3);
#pragma unroll
    for (int ks = 0; ks < 2; ++ks) {
      const short8 qf = ks ? qf1 : qf0;
#pragma unroll
      for (int n = 0; n < 4; ++n) {
        const int rK = ((n >> 1) << 5) + ((n & 1) << 2) + rKb;
        const short8 kf =
            *(const short8*)(sK + rK * 64 + (((ks * 4 + lk8) ^ (rK & 7)) << 3));
        accS[n] = MFMA_BF16(kf, qf, accS[n]);
      }
    }

    // per-lane softmax over this lane's 16 keys (row q = qrow)
    float sv[4][4];
    float mx = -1e30f;
#pragma unroll
    for (int n = 0; n < 4; ++n)
#pragma unroll
      for (int r = 0; r < 4; ++r) {
        const int key = k0 + ((n >> 1) << 5) + (lk8 << 3) + ((n & 1) << 2) + r;
        float s = accS[n][r];
        s = (key > qrow) ? -1e30f : s;
        sv[n][r] = s;
        mx = fmaxf(mx, s);
      }
    mx = fmaxf(mx, __shfl_xor(mx, 16));
    mx = fmaxf(mx, __shfl_xor(mx, 32));
    const float mnew = fmaxf(m_run, mx);
    const float sf = exp2f(m_run - mnew);  // scores are in log2 units
    m_run = mnew;

    float rs = 0.f;
    unsigned int w[4][2];
#pragma unroll
    for (int n = 0; n < 4; ++n)
#pragma unroll
      for (int rp = 0; rp < 2; ++rp) {
        const float ea = exp2f(sv[n][2 * rp] - mnew);
        const float eb = exp2f(sv[n][2 * rp + 1] - mnew);
        rs += ea + eb;
        w[n][rp] = (unsigned int)(unsigned short)f2bf(ea) |
                   ((unsigned int)(unsigned short)f2bf(eb) << 16);
      }
    lsum = lsum * sf + rs;

    float sfq[4];
#pragma unroll
    for (int r = 0; r < 4; ++r)
      sfq[r] = __shfl(sf, (lane & 48) | (lk8 * 4 + r));
#pragma unroll
    for (int n = 0; n < 4; ++n)
#pragma unroll
      for (int r = 0; r < 4; ++r) accO[n][r] *= sfq[r];

    union { short8 s; unsigned int u[4]; } paf0, paf1;
#pragma unroll
    for (int tt = 0; tt < 4; ++tt) {
      paf0.u[tt] = w[tt >> 1][tt & 1];
      paf1.u[tt] = w[2 + (tt >> 1)][tt & 1];
    }

#pragma unroll
    for (int n = 0; n < 4; ++n) {
      const int dh = n * 16 + lrow;
      const short8 vf0 = *(const short8*)(sV + dh * 64 + ((lk8 ^ (dh & 7)) << 3));
      const short8 vf1 =
          *(const short8*)(sV + dh * 64 + (((4 + lk8) ^ (dh & 7)) << 3));
      accO[n] = MFMA_BF16(paf0.s, vf0, accO[n]);
      accO[n] = MFMA_BF16(paf1.s, vf1, accO[n]);
    }
    __syncthreads();
  }

  float ls = lsum;
  ls += __shfl_xor(ls, 16);
  ls += __shfl_xor(ls, 32);
  const float invown = 1.f / ls;
  float invq[4];
#pragma unroll
  for (int r = 0; r < 4; ++r)
    invq[r] = __shfl(invown, (lane & 48) | (lk8 * 4 + r));

  const int bb = bh / 12, hh = bh % 12;
#pragma unroll
  for (int n = 0; n < 4; ++n)
#pragma unroll
    for (int r = 0; r < 4; ++r) {
      const int row = q0 + wv * 16 + lk8 * 4 + r;
      const float ov = accO[n][r] * invq[r];
      o[((size_t)(bb * 1024 + row)) * 768 + hh * 64 + n * 16 + lrow] = f2bf(ov);
    }
}

// ---------------------------------------------------------------------------
extern "C" void kernel_launch(void* const* d_in, const int* in_sizes, int n_in,
                              void* d_out, int out_size, void* d_ws, size_t ws_size,
                              hipStream_t stream) {
  const int* idx = (const int*)d_in[0];
  const float* wte = (const float*)d_in[1];
  const float* wpe = (const float*)d_in[2];
  const float* ln1_g = (const float*)d_in[3];
  const float* ln1_b = (const float*)d_in[4];
  const float* wq = (const float*)d_in[5];
  const float* bq = (const float*)d_in[6];
  const float* wk = (const float*)d_in[7];
  const float* bk = (const float*)d_in[8];
  const float* wv = (const float*)d_in[9];
  const float* bv = (const float*)d_in[10];
  const float* wo = (const float*)d_in[11];
  const float* bo = (const float*)d_in[12];
  const float* ln2_g = (const float*)d_in[13];
  const float* ln2_b = (const float*)d_in[14];
  const float* w1 = (const float*)d_in[15];
  const float* b1 = (const float*)d_in[16];
  const float* w2 = (const float*)d_in[17];
  const float* b2 = (const float*)d_in[18];
  const float* lnf_g = (const float*)d_in[19];
  const float* lnf_b = (const float*)d_in[20];
  const float* lm_w = (const float*)d_in[21];
  float* out = (float*)d_out;

  char* base = (char*)d_ws;
  size_t off = 0;
  auto alloc = [&](size_t bytes) {
    char* r = base + off;
    off = (off + bytes + 255) & ~(size_t)255;
    return r;
  };
  short* lmT = (short*)alloc((size_t)50304 * 768 * 2);
  float* x = (float*)alloc((size_t)4096 * 768 * 4);
  short* h = (short*)alloc((size_t)4096 * 768 * 2);
  short* qb = (short*)alloc((size_t)4096 * 768 * 2);
  short* kb = (short*)alloc((size_t)4096 * 768 * 2);
  short* vtb = (short*)alloc((size_t)4096 * 768 * 2);
  short* ob = (short*)alloc((size_t)4096 * 768 * 2);
  short* ff = (short*)alloc((size_t)4096 * 3072 * 2);

  const size_t LW = 7077888;  // elements per layer weight block
  const size_t dd = (size_t)768 * 768;
  const bool big = (off + (size_t)12 * LW * 2 + 256 <= ws_size);
  short* wAll = nullptr;
  short *wqkvT = nullptr, *woT = nullptr, *w1T = nullptr, *w2T = nullptr;
  if (big) {
    wAll = (short*)alloc((size_t)12 * LW * 2);
  } else {
    wqkvT = (short*)alloc((size_t)2304 * 768 * 2);
    woT = (short*)alloc((size_t)768 * 768 * 2);
    w1T = (short*)alloc((size_t)3072 * 768 * 2);
    w2T = (short*)alloc((size_t)768 * 3072 * 2);
    if (off > ws_size) return;
  }

  const dim3 tb(32, 8);
  transpose_convert<<<dim3(1572, 24, 1), tb, 0, stream>>>(lm_w, lmT, 768, 50257, 0, 0);
  if (big) {
    transpose_convert<<<dim3(24, 24, 12), tb, 0, stream>>>(wq, wAll + 0, 768, 768, dd, LW);
    transpose_convert<<<dim3(24, 24, 12), tb, 0, stream>>>(wk, wAll + 589824, 768, 768, dd, LW);
    transpose_convert<<<dim3(24, 24, 12), tb, 0, stream>>>(wv, wAll + 1179648, 768, 768, dd, LW);
    transpose_convert<<<dim3(24, 24, 12), tb, 0, stream>>>(wo, wAll + 1769472, 768, 768, dd, LW);
    transpose_convert<<<dim3(96, 24, 12), tb, 0, stream>>>(w1, wAll + 2359296, 768, 3072,
                                                           (size_t)768 * 3072, LW);
    transpose_convert<<<dim3(24, 96, 12), tb, 0, stream>>>(w2, wAll + 4718592, 3072, 768,
                                                           (size_t)3072 * 768, LW);
  }
  embed_kernel<<<4096, 256, 0, stream>>>(idx, wte, wpe, x);

  for (int l = 0; l < 12; ++l) {
    const short *pQKV, *pWO, *pW1, *pW2;
    if (big) {
      short* wl = wAll + (size_t)l * LW;
      pQKV = wl;
      pWO = wl + 1769472;
      pW1 = wl + 2359296;
      pW2 = wl + 4718592;
    } else {
      transpose_convert<<<dim3(24, 24, 1), tb, 0, stream>>>(wq + l * dd, wqkvT, 768, 768, 0, 0);
      transpose_convert<<<dim3(24, 24, 1), tb, 0, stream>>>(wk + l * dd, wqkvT + dd, 768, 768, 0, 0);
      transpose_convert<<<dim3(24, 24, 1), tb, 0, stream>>>(wv + l * dd, wqkvT + 2 * dd, 768, 768, 0, 0);
      transpose_convert<<<dim3(24, 24, 1), tb, 0, stream>>>(wo + l * dd, woT, 768, 768, 0, 0);
      transpose_convert<<<dim3(96, 24, 1), tb, 0, stream>>>(w1 + (size_t)l * 768 * 3072, w1T, 768, 3072, 0, 0);
      transpose_convert<<<dim3(24, 96, 1), tb, 0, stream>>>(w2 + (size_t)l * 3072 * 768, w2T, 3072, 768, 0, 0);
      pQKV = wqkvT; pWO = woT; pW1 = w1T; pW2 = w2T;
    }

    ln_kernel<<<4096, 256, 0, stream>>>(x, ln1_g + l * 768, ln1_b + l * 768, h);
    gemm_kernel<128, 64, EPI_QKV><<<dim3(32, 36), 256, 0, stream>>>(
        h, pQKV, 768, bq + l * 768, bk + l * 768, bv + l * 768, nullptr, qb, kb, vtb);
    attn_kernel<<<dim3(48, 16), 256, 0, stream>>>(qb, kb, vtb, ob);
    gemm_kernel<64, 64, EPI_RESID><<<dim3(64, 12), 256, 0, stream>>>(
        ob, pWO, 768, bo + l * 768, nullptr, nullptr, x, nullptr, nullptr, nullptr);
    ln_kernel<<<4096, 256, 0, stream>>>(x, ln2_g + l * 768, ln2_b + l * 768, h);
    gemm_kernel<128, 64, EPI_GELU><<<dim3(32, 48), 256, 0, stream>>>(
        h, pW1, 768, b1 + l * 3072, nullptr, nullptr, nullptr, ff, nullptr, nullptr);
    gemm_kernel<64, 64, EPI_RESID><<<dim3(64, 12), 256, 0, stream>>>(
        ff, pW2, 3072, b2 + l * 768, nullptr, nullptr, x, nullptr, nullptr, nullptr);
  }

  ln_kernel<<<4096, 256, 0, stream>>>(x, lnf_g, lnf_b, h);
  gemm_lm_kernel<<<dim3(16, 393), 512, 0, stream>>>(h, lmT, out);
}